// Round 4
// baseline (1384.061 us; speedup 1.0000x reference)
//
#include <hip/hip_runtime.h>
#include <math.h>

// Problem constants
#define B_  16
#define LU_ 2048
#define LV_ 2048
#define D_  1024
#define NT_ (LV_ / 128)   // 16 v-tiles of 128
#define MB_ (1024ull * 1024ull)

typedef __attribute__((ext_vector_type(8))) short bf16x8;
typedef __attribute__((ext_vector_type(16))) float f32x16;

__device__ __forceinline__ unsigned short f2bf(float x) {
    unsigned int u = __builtin_bit_cast(unsigned int, x);
    u += 0x7fffu + ((u >> 16) & 1u);          // RNE
    return (unsigned short)(u >> 16);
}
__device__ __forceinline__ float bf2f(unsigned short h) {
    unsigned int u = ((unsigned int)h) << 16;
    return __builtin_bit_cast(float, u);
}

__device__ __forceinline__ void gload_lds16(const void* g, void* l) {
    __builtin_amdgcn_global_load_lds(
        (const __attribute__((address_space(1))) void*)g,
        (__attribute__((address_space(3))) void*)l, 16, 0, 0);
}

// ---------------------------------------------------------------------------
// K0: per-batch valid length from mask, with byte-vs-int32 layout detection.
__global__ void lengths_kernel(const void* __restrict__ mask, int* __restrict__ lengths) {
    __shared__ int viol;
    __shared__ int cnt[B_];
    const int t = threadIdx.x;
    if (t == 0) viol = 0;
    if (t < B_) cnt[t] = 0;
    __syncthreads();
    const unsigned char* mb = (const unsigned char*)mask;
    int local = 0;
    for (int i = t; i < B_ * LV_ - 1; i += 256) {
        if (((i + 1) % LV_) != 0) {
            if (mb[i] != 0 && mb[i + 1] == 0) local++;
        }
    }
    if (local) atomicAdd(&viol, local);
    __syncthreads();
    const bool is_i32 = (viol > 0);
    const int b = t >> 4, s = t & 15;
    int c = 0;
    if (is_i32) {
        const int* mi = (const int*)mask;
        for (int v2 = s; v2 < LV_; v2 += 16) c += (mi[b * LV_ + v2] == 0) ? 1 : 0;
    } else {
        for (int v2 = s; v2 < LV_; v2 += 16) c += (mb[b * LV_ + v2] == 0) ? 1 : 0;
    }
    atomicAdd(&cnt[b], c);
    __syncthreads();
    if (t < B_) lengths[t] = cnt[t];
}

// ---------------------------------------------------------------------------
// K1: fp32 -> bf16 hi/lo split (elementwise, 8 elems/thread, grid-stride)
__global__ __launch_bounds__(256) void split_kernel(
    const float* __restrict__ X, unsigned short* __restrict__ hi,
    unsigned short* __restrict__ lo, long n8) {
    const long stride = (long)gridDim.x * 256;
    for (long i = (long)blockIdx.x * 256 + threadIdx.x; i < n8; i += stride) {
        float4 x0 = ((const float4*)X)[i * 2];
        float4 x1 = ((const float4*)X)[i * 2 + 1];
        float xv[8] = {x0.x, x0.y, x0.z, x0.w, x1.x, x1.y, x1.z, x1.w};
        bf16x8 h, l;
#pragma unroll
        for (int j = 0; j < 8; j++) {
            unsigned short hh = f2bf(xv[j]);
            h[j] = (short)hh;
            l[j] = (short)f2bf(xv[j] - bf2f(hh));
        }
        ((bf16x8*)hi)[i] = h;
        ((bf16x8*)lo)[i] = l;
    }
}

// ---------------------------------------------------------------------------
// K2: Y = relu(X @ W^T + b) as bf16 hi/lo. 3-term hi/lo, 32x32x16 MFMA.
// 128x128 tile, BK=32, 4 waves of 64x64, gload_lds + chunk swizzle.
__global__ __launch_bounds__(256, 2) void proj_kernel(
    const unsigned short* __restrict__ Xh, const unsigned short* __restrict__ Xl,
    const unsigned short* __restrict__ Wh, const unsigned short* __restrict__ Wl,
    const float* __restrict__ bias,
    unsigned short* __restrict__ Yhi, unsigned short* __restrict__ Ylo) {
    __shared__ alignas(16) unsigned short sAh[128 * 32], sAl[128 * 32],
                                          sBh[128 * 32], sBl[128 * 32];
    const int t = threadIdx.x, lane = t & 63, w = t >> 6;
    const int wr = (w >> 1) * 64, wc = (w & 1) * 64;
    const int l5 = lane >> 5, l31 = lane & 31;
    const int row0 = blockIdx.x * 128, col0 = blockIdx.y * 128;

    // staging geometry (R2-proven)
    const int sr0 = w * 16 + (lane >> 2);
    const int sr1 = 64 + sr0;
    const int c0 = (lane & 3) ^ ((sr0 >> 1) & 3);
    const int c1 = (lane & 3) ^ ((sr1 >> 1) & 3);
    const size_t ao0 = (size_t)(row0 + sr0) * D_ + c0 * 8;
    const size_t ao1 = (size_t)(row0 + sr1) * D_ + c1 * 8;
    const size_t bo0 = (size_t)(col0 + sr0) * D_ + c0 * 8;
    const size_t bo1 = (size_t)(col0 + sr1) * D_ + c1 * 8;
    const int db0 = (w * 16) * 32;
    const int db1 = (64 + w * 16) * 32;

    // fragment read offsets: [blk][k-half], row r, logical chunk kh*2+l5
    int aoff[2][2], boff[2][2];
#pragma unroll
    for (int ar = 0; ar < 2; ar++) {
        const int r = wr + ar * 32 + l31;
#pragma unroll
        for (int kh = 0; kh < 2; kh++)
            aoff[ar][kh] = r * 32 + (((kh * 2 + l5) ^ ((r >> 1) & 3)) * 8);
    }
#pragma unroll
    for (int br = 0; br < 2; br++) {
        const int r = wc + br * 32 + l31;
#pragma unroll
        for (int kh = 0; kh < 2; kh++)
            boff[br][kh] = r * 32 + (((kh * 2 + l5) ^ ((r >> 1) & 3)) * 8);
    }

    f32x16 acc[2][2];
#pragma unroll
    for (int ar = 0; ar < 2; ar++)
#pragma unroll
        for (int br = 0; br < 2; br++)
#pragma unroll
            for (int i = 0; i < 16; i++) acc[ar][br][i] = 0.f;

    for (int k0 = 0; k0 < D_; k0 += 32) {
        __syncthreads();
        gload_lds16(Xh + ao0 + k0, &sAh[db0]);
        gload_lds16(Xh + ao1 + k0, &sAh[db1]);
        gload_lds16(Xl + ao0 + k0, &sAl[db0]);
        gload_lds16(Xl + ao1 + k0, &sAl[db1]);
        gload_lds16(Wh + bo0 + k0, &sBh[db0]);
        gload_lds16(Wh + bo1 + k0, &sBh[db1]);
        gload_lds16(Wl + bo0 + k0, &sBl[db0]);
        gload_lds16(Wl + bo1 + k0, &sBl[db1]);
        __syncthreads();
#pragma unroll
        for (int kh = 0; kh < 2; kh++) {
            bf16x8 ah[2], al[2], bh[2], bl[2];
#pragma unroll
            for (int ar = 0; ar < 2; ar++) {
                ah[ar] = *(const bf16x8*)&sAh[aoff[ar][kh]];
                al[ar] = *(const bf16x8*)&sAl[aoff[ar][kh]];
            }
#pragma unroll
            for (int br = 0; br < 2; br++) {
                bh[br] = *(const bf16x8*)&sBh[boff[br][kh]];
                bl[br] = *(const bf16x8*)&sBl[boff[br][kh]];
            }
#pragma unroll
            for (int ar = 0; ar < 2; ar++)
#pragma unroll
                for (int br = 0; br < 2; br++) {
                    acc[ar][br] = __builtin_amdgcn_mfma_f32_32x32x16_bf16(ah[ar], bh[br], acc[ar][br], 0, 0, 0);
                    acc[ar][br] = __builtin_amdgcn_mfma_f32_32x32x16_bf16(ah[ar], bl[br], acc[ar][br], 0, 0, 0);
                    acc[ar][br] = __builtin_amdgcn_mfma_f32_32x32x16_bf16(al[ar], bh[br], acc[ar][br], 0, 0, 0);
                }
        }
    }

    // epilogue: relu + hi/lo split store. C: col=l31(+32*br), row=(i&3)+8*(i>>2)+4*l5
#pragma unroll
    for (int br = 0; br < 2; br++) {
        const int col = col0 + wc + br * 32 + l31;
        const float bv = bias[col];
#pragma unroll
        for (int ar = 0; ar < 2; ar++) {
#pragma unroll
            for (int i = 0; i < 16; i++) {
                const int row = row0 + wr + ar * 32 + (i & 3) + 8 * (i >> 2) + 4 * l5;
                float y = fmaxf(acc[ar][br][i] + bv, 0.f);
                const unsigned short hh = f2bf(y);
                const size_t idx = (size_t)row * D_ + col;
                Yhi[idx] = hh;
                Ylo[idx] = f2bf(y - bf2f(hh));
            }
        }
    }
}

// ---------------------------------------------------------------------------
// K3: v fp32 [B][LV][D] -> vT bf16 [B][D][LV]
__global__ __launch_bounds__(256) void transpose_v_kernel(
    const float* __restrict__ V, unsigned short* __restrict__ VT) {
    __shared__ unsigned short s[64 * 72];
    const int b = blockIdx.z;
    const int v0 = blockIdx.x * 64, d0 = blockIdx.y * 64;
    const int t = threadIdx.x;
    {
        const int r = t >> 2, q = (t & 3) * 16;
        const float* src = V + ((size_t)b * LV_ + v0 + r) * D_ + d0 + q;
#pragma unroll
        for (int i = 0; i < 4; i++) {
            float4 x = ((const float4*)src)[i];
            s[r * 72 + q + i * 4 + 0] = f2bf(x.x);
            s[r * 72 + q + i * 4 + 1] = f2bf(x.y);
            s[r * 72 + q + i * 4 + 2] = f2bf(x.z);
            s[r * 72 + q + i * 4 + 3] = f2bf(x.w);
        }
    }
    __syncthreads();
    {
        const int d = t >> 2, vq = (t & 3) * 16;
        bf16x8 t0, t1;
#pragma unroll
        for (int j = 0; j < 8; j++) t0[j] = (short)s[(vq + j) * 72 + d];
#pragma unroll
        for (int j = 0; j < 8; j++) t1[j] = (short)s[(vq + 8 + j) * 72 + d];
        unsigned short* dst = VT + ((size_t)b * D_ + d0 + d) * LV_ + v0 + vq;
        ((bf16x8*)dst)[0] = t0;
        ((bf16x8*)dst)[1] = t1;
    }
}

// ---------------------------------------------------------------------------
// K4: logits tile kernel. Grid (LU/128, NT, B). One 128x128 S-tile per WG,
// 32x32x16 MFMA 3-term, per-tile softmax stats, P'=exp(S-m_t) bf16.
__global__ __launch_bounds__(256, 2) void attn_logits_kernel(
    const unsigned short* __restrict__ Uh, const unsigned short* __restrict__ Ul,
    const unsigned short* __restrict__ Vh, const unsigned short* __restrict__ Vl,
    const int* __restrict__ lengths,
    unsigned short* __restrict__ Pp, float* __restrict__ m_used,
    float* __restrict__ Z_used) {
    __shared__ alignas(16) unsigned short sUh[128 * 32], sUl[128 * 32],
                                          sVh[128 * 32], sVl[128 * 32];
    const int b = blockIdx.z, ut = blockIdx.x, vt = blockIdx.y;
    const int t = threadIdx.x, lane = t & 63, w = t >> 6;
    const int wr = (w >> 1) * 64, wc = (w & 1) * 64;
    const int l5 = lane >> 5, l31 = lane & 31;
    const int length = lengths[b];
    const int row0 = ut * 128, col0 = vt * 128;

    if (col0 >= length) {   // fully-masked tile: zero P', degenerate stats
        const bf16x8 zv = {0, 0, 0, 0, 0, 0, 0, 0};
        for (int i = t; i < 128 * 16; i += 256) {
            const int r = i >> 4, c = (i & 15) * 8;
            *(bf16x8*)&Pp[(size_t)(b * LU_ + row0 + r) * LV_ + col0 + c] = zv;
        }
        if (t < 128) {
            const size_t row = (size_t)b * LU_ + row0 + t;
            m_used[row * NT_ + vt] = -__builtin_inff();
            Z_used[row * NT_ + vt] = 0.f;
        }
        return;
    }

    const int sr0 = w * 16 + (lane >> 2);
    const int sr1 = 64 + sr0;
    const int c0 = (lane & 3) ^ ((sr0 >> 1) & 3);
    const int c1 = (lane & 3) ^ ((sr1 >> 1) & 3);
    const size_t uo0 = ((size_t)b * LU_ + row0 + sr0) * D_ + c0 * 8;
    const size_t uo1 = ((size_t)b * LU_ + row0 + sr1) * D_ + c1 * 8;
    const size_t vo0 = ((size_t)b * LV_ + col0 + sr0) * D_ + c0 * 8;
    const size_t vo1 = ((size_t)b * LV_ + col0 + sr1) * D_ + c1 * 8;
    const int db0 = (w * 16) * 32;
    const int db1 = (64 + w * 16) * 32;

    int aoff[2][2], boff[2][2];
#pragma unroll
    for (int ar = 0; ar < 2; ar++) {
        const int r = wr + ar * 32 + l31;
#pragma unroll
        for (int kh = 0; kh < 2; kh++)
            aoff[ar][kh] = r * 32 + (((kh * 2 + l5) ^ ((r >> 1) & 3)) * 8);
    }
#pragma unroll
    for (int br = 0; br < 2; br++) {
        const int r = wc + br * 32 + l31;
#pragma unroll
        for (int kh = 0; kh < 2; kh++)
            boff[br][kh] = r * 32 + (((kh * 2 + l5) ^ ((r >> 1) & 3)) * 8);
    }

    f32x16 acc[2][2];
#pragma unroll
    for (int ar = 0; ar < 2; ar++)
#pragma unroll
        for (int br = 0; br < 2; br++)
#pragma unroll
            for (int i = 0; i < 16; i++) acc[ar][br][i] = 0.f;

    for (int k0 = 0; k0 < D_; k0 += 32) {
        __syncthreads();
        gload_lds16(Uh + uo0 + k0, &sUh[db0]);
        gload_lds16(Uh + uo1 + k0, &sUh[db1]);
        gload_lds16(Ul + uo0 + k0, &sUl[db0]);
        gload_lds16(Ul + uo1 + k0, &sUl[db1]);
        gload_lds16(Vh + vo0 + k0, &sVh[db0]);
        gload_lds16(Vh + vo1 + k0, &sVh[db1]);
        gload_lds16(Vl + vo0 + k0, &sVl[db0]);
        gload_lds16(Vl + vo1 + k0, &sVl[db1]);
        __syncthreads();
#pragma unroll
        for (int kh = 0; kh < 2; kh++) {
            bf16x8 ah[2], al[2], bh[2], bl[2];
#pragma unroll
            for (int ar = 0; ar < 2; ar++) {
                ah[ar] = *(const bf16x8*)&sUh[aoff[ar][kh]];
                al[ar] = *(const bf16x8*)&sUl[aoff[ar][kh]];
            }
#pragma unroll
            for (int br = 0; br < 2; br++) {
                bh[br] = *(const bf16x8*)&sVh[boff[br][kh]];
                bl[br] = *(const bf16x8*)&sVl[boff[br][kh]];
            }
#pragma unroll
            for (int ar = 0; ar < 2; ar++)
#pragma unroll
                for (int br = 0; br < 2; br++) {
                    acc[ar][br] = __builtin_amdgcn_mfma_f32_32x32x16_bf16(ah[ar], bh[br], acc[ar][br], 0, 0, 0);
                    acc[ar][br] = __builtin_amdgcn_mfma_f32_32x32x16_bf16(ah[ar], bl[br], acc[ar][br], 0, 0, 0);
                    acc[ar][br] = __builtin_amdgcn_mfma_f32_32x32x16_bf16(al[ar], bh[br], acc[ar][br], 0, 0, 0);
                }
        }
    }

    // ---- per-tile softmax stats ----
    __syncthreads();
    float* sMax = (float*)sUh;           // [128][2]
    float* sSum = sMax + 256;            // [128][2]
    const bool valid0 = (col0 + wc + l31) < length;
    const bool valid1 = (col0 + wc + 32 + l31) < length;

    // pass 1: row max over this wave's 64 cols
#pragma unroll
    for (int ar = 0; ar < 2; ar++) {
#pragma unroll
        for (int i = 0; i < 16; i++) {
            float mt = fmaxf(valid0 ? acc[ar][0][i] : -__builtin_inff(),
                             valid1 ? acc[ar][1][i] : -__builtin_inff());
#pragma unroll
            for (int d = 1; d < 32; d <<= 1) mt = fmaxf(mt, __shfl_xor(mt, d));
            if (l31 == 0) {
                const int rl = wr + ar * 32 + (i & 3) + 8 * (i >> 2) + 4 * l5;
                sMax[rl * 2 + (w & 1)] = mt;
            }
        }
    }
    __syncthreads();
    // pass 2: p = exp(acc - m_row), store P', accumulate row sums
#pragma unroll
    for (int ar = 0; ar < 2; ar++) {
#pragma unroll
        for (int i = 0; i < 16; i++) {
            const int rl = wr + ar * 32 + (i & 3) + 8 * (i >> 2) + 4 * l5;
            const float mrow = fmaxf(sMax[rl * 2], sMax[rl * 2 + 1]);
            const float p0 = valid0 ? __expf(acc[ar][0][i] - mrow) : 0.f;
            const float p1 = valid1 ? __expf(acc[ar][1][i] - mrow) : 0.f;
            const size_t rg = ((size_t)b * LU_ + row0 + rl) * LV_ + col0 + wc;
            Pp[rg + l31] = f2bf(p0);
            Pp[rg + 32 + l31] = f2bf(p1);
            float rs = p0 + p1;
#pragma unroll
            for (int d = 1; d < 32; d <<= 1) rs += __shfl_xor(rs, d);
            if (l31 == 0) sSum[rl * 2 + (w & 1)] = rs;
        }
    }
    __syncthreads();
    if (t < 128) {
        const float m_t = fmaxf(sMax[t * 2], sMax[t * 2 + 1]);
        const float z = sSum[t * 2] + sSum[t * 2 + 1];
        const size_t row = (size_t)b * LU_ + row0 + t;
        m_used[row * NT_ + vt] = m_t;
        Z_used[row * NT_ + vt] = z;
    }
}

// ---------------------------------------------------------------------------
// K5: combine per-tile stats -> Sc[row][vt] = exp(m_t - m_fin) / Z
__global__ __launch_bounds__(256) void stats_combine_kernel(
    const float* __restrict__ m_used, const float* __restrict__ Z_used,
    float* __restrict__ Sc) {
    const int row = blockIdx.x * 256 + threadIdx.x;
    float mv[NT_];
    float m = -__builtin_inff();
#pragma unroll
    for (int i = 0; i < NT_; i++) {
        mv[i] = m_used[(size_t)row * NT_ + i];
        m = fmaxf(m, mv[i]);
    }
    float ev[NT_];
    float z = 0.f;
#pragma unroll
    for (int i = 0; i < NT_; i++) {
        ev[i] = __expf(mv[i] - m);
        z += Z_used[(size_t)row * NT_ + i] * ev[i];
    }
    const float inv = 1.f / z;
#pragma unroll
    for (int i = 0; i < NT_; i++) Sc[(size_t)row * NT_ + i] = ev[i] * inv;
}

// ---------------------------------------------------------------------------
// K6: out = sum_vt Sc(row,vt) * (P'_vt @ V_vt). 128x128 tile, BK=64,
// 4 waves 2x2 of 64x64, 32x32x16 MFMA, scale folded per v-tile.
__global__ __launch_bounds__(256, 2) void pv_gemm_kernel(
    const unsigned short* __restrict__ Pp, const unsigned short* __restrict__ VT,
    const float* __restrict__ Sc, float* __restrict__ Out) {
    __shared__ alignas(16) unsigned short sA[128 * 64], sB[128 * 64];
    const int b = blockIdx.z, bm = blockIdx.x, bn = blockIdx.y;
    const int t = threadIdx.x, lane = t & 63, w = t >> 6;
    const int wr = (w >> 1) * 64, wc = (w & 1) * 64;
    const int l5 = lane >> 5, l31 = lane & 31;

    // staging (R2-proven): wave w rows [w*32,+32), issue i rows [w*32+i*8,+8)
    size_t aog[4], bog[4];
    int dbs[4];
#pragma unroll
    for (int i = 0; i < 4; i++) {
        const int r = w * 32 + i * 8 + (lane >> 3);
        const int cg = (lane & 7) ^ (r & 7);
        aog[i] = ((size_t)b * LU_ + bm * 128 + r) * LV_ + cg * 8;
        bog[i] = ((size_t)b * D_ + bn * 128 + r) * LV_ + cg * 8;
        dbs[i] = (w * 32 + i * 8) * 64;
    }
    // fragment offsets: [blk][kk], row r, logical chunk kk*2+l5 of 8
    int aoff[2][4], boff[2][4];
#pragma unroll
    for (int ar = 0; ar < 2; ar++) {
        const int r = wr + ar * 32 + l31;
#pragma unroll
        for (int kk = 0; kk < 4; kk++)
            aoff[ar][kk] = r * 64 + (((kk * 2 + l5) ^ (r & 7)) * 8);
    }
#pragma unroll
    for (int br = 0; br < 2; br++) {
        const int r = wc + br * 32 + l31;
#pragma unroll
        for (int kk = 0; kk < 4; kk++)
            boff[br][kk] = r * 64 + (((kk * 2 + l5) ^ (r & 7)) * 8);
    }

    f32x16 acc[2][2];
#pragma unroll
    for (int ar = 0; ar < 2; ar++)
#pragma unroll
        for (int br = 0; br < 2; br++)
#pragma unroll
            for (int i = 0; i < 16; i++) acc[ar][br][i] = 0.f;

    for (int vt = 0; vt < NT_; ++vt) {
        f32x16 part[2][2];
#pragma unroll
        for (int ar = 0; ar < 2; ar++)
#pragma unroll
            for (int br = 0; br < 2; br++)
#pragma unroll
                for (int i = 0; i < 16; i++) part[ar][br][i] = 0.f;

#pragma unroll 1
        for (int kb = 0; kb < 2; ++kb) {
            const int k0 = vt * 128 + kb * 64;
            __syncthreads();
#pragma unroll
            for (int i = 0; i < 4; i++) {
                gload_lds16(Pp + aog[i] + k0, &sA[dbs[i]]);
                gload_lds16(VT + bog[i] + k0, &sB[dbs[i]]);
            }
            __syncthreads();
#pragma unroll
            for (int kk = 0; kk < 4; kk++) {
                const bf16x8 a0 = *(const bf16x8*)&sA[aoff[0][kk]];
                const bf16x8 a1 = *(const bf16x8*)&sA[aoff[1][kk]];
                const bf16x8 b0 = *(const bf16x8*)&sB[boff[0][kk]];
                const bf16x8 b1 = *(const bf16x8*)&sB[boff[1][kk]];
                part[0][0] = __builtin_amdgcn_mfma_f32_32x32x16_bf16(a0, b0, part[0][0], 0, 0, 0);
                part[0][1] = __builtin_amdgcn_mfma_f32_32x32x16_bf16(a0, b1, part[0][1], 0, 0, 0);
                part[1][0] = __builtin_amdgcn_mfma_f32_32x32x16_bf16(a1, b0, part[1][0], 0, 0, 0);
                part[1][1] = __builtin_amdgcn_mfma_f32_32x32x16_bf16(a1, b1, part[1][1], 0, 0, 0);
            }
        }
#pragma unroll
        for (int ar = 0; ar < 2; ar++) {
#pragma unroll
            for (int i = 0; i < 16; i++) {
                const int row = bm * 128 + wr + ar * 32 + (i & 3) + 8 * (i >> 2) + 4 * l5;
                const float sc = Sc[((size_t)b * LU_ + row) * NT_ + vt];
                acc[ar][0][i] += sc * part[ar][0][i];
                acc[ar][1][i] += sc * part[ar][1][i];
            }
        }
    }

    float* Ob = Out + (size_t)b * LU_ * D_;
#pragma unroll
    for (int ar = 0; ar < 2; ar++) {
#pragma unroll
        for (int br = 0; br < 2; br++) {
            const int col = bn * 128 + wc + br * 32 + l31;
#pragma unroll
            for (int i = 0; i < 16; i++) {
                const int row = bm * 128 + wr + ar * 32 + (i & 3) + 8 * (i >> 2) + 4 * l5;
                Ob[(size_t)row * D_ + col] = acc[ar][br][i];
            }
        }
    }
}

// ---------------------------------------------------------------------------
extern "C" void kernel_launch(void* const* d_in, const int* in_sizes, int n_in,
                              void* d_out, int out_size, void* d_ws, size_t ws_size,
                              hipStream_t stream) {
    (void)in_sizes; (void)n_in; (void)out_size; (void)ws_size;
    const float* u    = (const float*)d_in[0];
    const float* v    = (const float*)d_in[1];
    const void*  vm   = d_in[2];
    const float* W    = (const float*)d_in[3];
    const float* bias = (const float*)d_in[4];
    float* out = (float*)d_out;
    char* ws = (char*)d_ws;

    // ws layout (max concurrent ~464 MB; xs region reused by Pp)
    unsigned short* xs_hi = (unsigned short*)(ws + 0 * MB_);      // 64MB (transient)
    unsigned short* xs_lo = (unsigned short*)(ws + 64 * MB_);     // 64MB (transient)
    unsigned short* Pp    = (unsigned short*)(ws + 0 * MB_);      // 128MB (aliases xs)
    unsigned short* vT    = (unsigned short*)(ws + 128 * MB_);    // 64MB
    unsigned short* W_hi  = (unsigned short*)(ws + 192 * MB_);    // 2MB
    unsigned short* W_lo  = (unsigned short*)(ws + 194 * MB_);    // 2MB
    int*   lengths = (int*)(ws + 196 * MB_);
    float* m_used  = (float*)(ws + 197 * MB_);                    // 2MB
    float* Z_used  = (float*)(ws + 199 * MB_);                    // 2MB
    float* Sc      = (float*)(ws + 201 * MB_);                    // 2MB
    unsigned short* u_hi = (unsigned short*)(ws + 208 * MB_);     // 64MB
    unsigned short* u_lo = (unsigned short*)(ws + 272 * MB_);
    unsigned short* v_hi = (unsigned short*)(ws + 336 * MB_);
    unsigned short* v_lo = (unsigned short*)(ws + 400 * MB_);     // end 464MB

    const long nW8 = (long)D_ * D_ / 8;
    const long nX8 = (long)B_ * LU_ * D_ / 8;

    lengths_kernel<<<1, 256, 0, stream>>>(vm, lengths);
    split_kernel<<<512, 256, 0, stream>>>(W, W_hi, W_lo, nW8);
    split_kernel<<<4096, 256, 0, stream>>>(u, xs_hi, xs_lo, nX8);
    proj_kernel<<<dim3(B_ * LU_ / 128, D_ / 128), 256, 0, stream>>>(
        xs_hi, xs_lo, W_hi, W_lo, bias, u_hi, u_lo);
    split_kernel<<<4096, 256, 0, stream>>>(v, xs_hi, xs_lo, nX8);
    proj_kernel<<<dim3(B_ * LV_ / 128, D_ / 128), 256, 0, stream>>>(
        xs_hi, xs_lo, W_hi, W_lo, bias, v_hi, v_lo);
    transpose_v_kernel<<<dim3(LV_ / 64, D_ / 64, B_), 256, 0, stream>>>(v, vT);
    attn_logits_kernel<<<dim3(LU_ / 128, NT_, B_), 256, 0, stream>>>(
        u_hi, u_lo, v_hi, v_lo, lengths, Pp, m_used, Z_used);
    stats_combine_kernel<<<B_ * LU_ / 256, 256, 0, stream>>>(m_used, Z_used, Sc);
    pv_gemm_kernel<<<dim3(LU_ / 128, D_ / 128, B_), 256, 0, stream>>>(Pp, vT, Sc, out);
}

// Round 5
// 1134.979 us; speedup vs baseline: 1.2195x; 1.2195x over previous
//
#include <hip/hip_runtime.h>
#include <math.h>

// Problem constants
#define B_  16
#define LU_ 2048
#define LV_ 2048
#define D_  1024
#define NT_ (LV_ / 128)   // 16 v-tiles of 128
#define MB_ (1024ull * 1024ull)

typedef __attribute__((ext_vector_type(8))) short bf16x8;
typedef __attribute__((ext_vector_type(4))) float f32x4;

__device__ __forceinline__ unsigned short f2bf(float x) {
    unsigned int u = __builtin_bit_cast(unsigned int, x);
    u += 0x7fffu + ((u >> 16) & 1u);          // RNE
    return (unsigned short)(u >> 16);
}
__device__ __forceinline__ float bf2f(unsigned short h) {
    unsigned int u = ((unsigned int)h) << 16;
    return __builtin_bit_cast(float, u);
}

__device__ __forceinline__ void gload_lds16(const void* g, void* l) {
    __builtin_amdgcn_global_load_lds(
        (const __attribute__((address_space(1))) void*)g,
        (__attribute__((address_space(3))) void*)l, 16, 0, 0);
}

// ---------------------------------------------------------------------------
// K0: per-batch valid length from mask, with byte-vs-int32 layout detection.
__global__ void lengths_kernel(const void* __restrict__ mask, int* __restrict__ lengths) {
    __shared__ int viol;
    __shared__ int cnt[B_];
    const int t = threadIdx.x;
    if (t == 0) viol = 0;
    if (t < B_) cnt[t] = 0;
    __syncthreads();
    const unsigned char* mb = (const unsigned char*)mask;
    int local = 0;
    for (int i = t; i < B_ * LV_ - 1; i += 256) {
        if (((i + 1) % LV_) != 0) {
            if (mb[i] != 0 && mb[i + 1] == 0) local++;
        }
    }
    if (local) atomicAdd(&viol, local);
    __syncthreads();
    const bool is_i32 = (viol > 0);
    const int b = t >> 4, s = t & 15;
    int c = 0;
    if (is_i32) {
        const int* mi = (const int*)mask;
        for (int v2 = s; v2 < LV_; v2 += 16) c += (mi[b * LV_ + v2] == 0) ? 1 : 0;
    } else {
        for (int v2 = s; v2 < LV_; v2 += 16) c += (mb[b * LV_ + v2] == 0) ? 1 : 0;
    }
    atomicAdd(&cnt[b], c);
    __syncthreads();
    if (t < B_) lengths[t] = cnt[t];
}

// ---------------------------------------------------------------------------
// K1: fp32 -> bf16 hi/lo split (elementwise, 8 elems/thread, grid-stride)
__global__ __launch_bounds__(256) void split_kernel(
    const float* __restrict__ X, unsigned short* __restrict__ hi,
    unsigned short* __restrict__ lo, long n8) {
    const long stride = (long)gridDim.x * 256;
    for (long i = (long)blockIdx.x * 256 + threadIdx.x; i < n8; i += stride) {
        float4 x0 = ((const float4*)X)[i * 2];
        float4 x1 = ((const float4*)X)[i * 2 + 1];
        float xv[8] = {x0.x, x0.y, x0.z, x0.w, x1.x, x1.y, x1.z, x1.w};
        bf16x8 h, l;
#pragma unroll
        for (int j = 0; j < 8; j++) {
            unsigned short hh = f2bf(xv[j]);
            h[j] = (short)hh;
            l[j] = (short)f2bf(xv[j] - bf2f(hh));
        }
        ((bf16x8*)hi)[i] = h;
        ((bf16x8*)lo)[i] = l;
    }
}

// ---------------------------------------------------------------------------
// K2: Y = relu(X @ W^T + b) as bf16 hi/lo. Pure-bf16 3-term MFMA GEMM.
// 128x128 tile, BK=32, 4 waves of 32 rows x 128 cols, gload_lds + swizzle.
// is_v != 0: skip row-blocks that are fully masked (lv0 >= lengths[b]).
__global__ __launch_bounds__(256, 2) void proj_kernel(
    const unsigned short* __restrict__ Xh, const unsigned short* __restrict__ Xl,
    const unsigned short* __restrict__ Wh, const unsigned short* __restrict__ Wl,
    const float* __restrict__ bias, const int* __restrict__ lengths, int is_v,
    unsigned short* __restrict__ Yhi, unsigned short* __restrict__ Ylo) {
    if (is_v) {
        const int bb = blockIdx.x >> 4;          // 16 blocks of 128 rows per batch
        const int lv0 = (blockIdx.x & 15) * 128;
        if (lv0 >= lengths[bb]) return;          // fully-masked row block
    }
    __shared__ alignas(16) unsigned short sAh[128 * 32], sAl[128 * 32],
                                          sBh[128 * 32], sBl[128 * 32];
    const int t = threadIdx.x, lane = t & 63, w = t >> 6;
    const int fr = lane & 15, fg = lane >> 4;
    const int row0 = blockIdx.x * 128, col0 = blockIdx.y * 128;

    // staging geometry: per wave, issue i in {0,1} covers rows [i*64+w*16, +16)
    const int sr0 = w * 16 + (lane >> 2);
    const int sr1 = 64 + sr0;
    const int c0 = (lane & 3) ^ ((sr0 >> 1) & 3);
    const int c1 = (lane & 3) ^ ((sr1 >> 1) & 3);
    const size_t ao0 = (size_t)(row0 + sr0) * D_ + c0 * 8;
    const size_t ao1 = (size_t)(row0 + sr1) * D_ + c1 * 8;
    const size_t bo0 = (size_t)(col0 + sr0) * D_ + c0 * 8;
    const size_t bo1 = (size_t)(col0 + sr1) * D_ + c1 * 8;
    const int db0 = (w * 16) * 32;
    const int db1 = (64 + w * 16) * 32;

    // fragment read offsets (swizzled), loop-invariant
    int aoff[2], boff[8];
#pragma unroll
    for (int m = 0; m < 2; m++) {
        const int r = w * 32 + m * 16 + fr;
        aoff[m] = r * 32 + (fg ^ ((r >> 1) & 3)) * 8;
    }
#pragma unroll
    for (int n = 0; n < 8; n++) {
        const int r = n * 16 + fr;
        boff[n] = r * 32 + (fg ^ ((r >> 1) & 3)) * 8;
    }

    const f32x4 fzero = {0.f, 0.f, 0.f, 0.f};
    f32x4 acc[2][8];
#pragma unroll
    for (int m = 0; m < 2; m++)
#pragma unroll
        for (int n = 0; n < 8; n++) acc[m][n] = fzero;

    for (int k0 = 0; k0 < D_; k0 += 32) {
        __syncthreads();
        gload_lds16(Xh + ao0 + k0, &sAh[db0]);
        gload_lds16(Xh + ao1 + k0, &sAh[db1]);
        gload_lds16(Xl + ao0 + k0, &sAl[db0]);
        gload_lds16(Xl + ao1 + k0, &sAl[db1]);
        gload_lds16(Wh + bo0 + k0, &sBh[db0]);
        gload_lds16(Wh + bo1 + k0, &sBh[db1]);
        gload_lds16(Wl + bo0 + k0, &sBl[db0]);
        gload_lds16(Wl + bo1 + k0, &sBl[db1]);
        __syncthreads();
        const bf16x8 ah0 = *(const bf16x8*)&sAh[aoff[0]];
        const bf16x8 ah1 = *(const bf16x8*)&sAh[aoff[1]];
        const bf16x8 al0 = *(const bf16x8*)&sAl[aoff[0]];
        const bf16x8 al1 = *(const bf16x8*)&sAl[aoff[1]];
#pragma unroll
        for (int n = 0; n < 8; n++) {
            const bf16x8 bh = *(const bf16x8*)&sBh[boff[n]];
            const bf16x8 bl = *(const bf16x8*)&sBl[boff[n]];
            acc[0][n] = __builtin_amdgcn_mfma_f32_16x16x32_bf16(ah0, bh, acc[0][n], 0, 0, 0);
            acc[0][n] = __builtin_amdgcn_mfma_f32_16x16x32_bf16(ah0, bl, acc[0][n], 0, 0, 0);
            acc[0][n] = __builtin_amdgcn_mfma_f32_16x16x32_bf16(al0, bh, acc[0][n], 0, 0, 0);
            acc[1][n] = __builtin_amdgcn_mfma_f32_16x16x32_bf16(ah1, bh, acc[1][n], 0, 0, 0);
            acc[1][n] = __builtin_amdgcn_mfma_f32_16x16x32_bf16(ah1, bl, acc[1][n], 0, 0, 0);
            acc[1][n] = __builtin_amdgcn_mfma_f32_16x16x32_bf16(al1, bh, acc[1][n], 0, 0, 0);
        }
    }

#pragma unroll
    for (int m = 0; m < 2; m++)
#pragma unroll
        for (int n = 0; n < 8; n++) {
            const int col = col0 + n * 16 + fr;
            const float bv = bias[col];
#pragma unroll
            for (int j = 0; j < 4; j++) {
                const int row = row0 + w * 32 + m * 16 + fg * 4 + j;
                float y = fmaxf(acc[m][n][j] + bv, 0.f);
                const unsigned short hh = f2bf(y);
                const size_t idx = (size_t)row * D_ + col;
                Yhi[idx] = hh;
                Ylo[idx] = f2bf(y - bf2f(hh));
            }
        }
}

// ---------------------------------------------------------------------------
// K3: v fp32 [B][LV][D] -> vT bf16 [B][D][LV]
__global__ __launch_bounds__(256) void transpose_v_kernel(
    const float* __restrict__ V, unsigned short* __restrict__ VT) {
    __shared__ unsigned short s[64 * 72];
    const int b = blockIdx.z;
    const int v0 = blockIdx.x * 64, d0 = blockIdx.y * 64;
    const int t = threadIdx.x;
    {
        const int r = t >> 2, q = (t & 3) * 16;
        const float* src = V + ((size_t)b * LV_ + v0 + r) * D_ + d0 + q;
#pragma unroll
        for (int i = 0; i < 4; i++) {
            float4 x = ((const float4*)src)[i];
            s[r * 72 + q + i * 4 + 0] = f2bf(x.x);
            s[r * 72 + q + i * 4 + 1] = f2bf(x.y);
            s[r * 72 + q + i * 4 + 2] = f2bf(x.z);
            s[r * 72 + q + i * 4 + 3] = f2bf(x.w);
        }
    }
    __syncthreads();
    {
        const int d = t >> 2, vq = (t & 3) * 16;
        bf16x8 t0, t1;
#pragma unroll
        for (int j = 0; j < 8; j++) t0[j] = (short)s[(vq + j) * 72 + d];
#pragma unroll
        for (int j = 0; j < 8; j++) t1[j] = (short)s[(vq + 8 + j) * 72 + d];
        unsigned short* dst = VT + ((size_t)b * D_ + d0 + d) * LV_ + v0 + vq;
        ((bf16x8*)dst)[0] = t0;
        ((bf16x8*)dst)[1] = t1;
    }
}

// ---------------------------------------------------------------------------
// K4: logits tile kernel. Grid (LU/128, NT, B). Each WG: one 128x128 S-tile,
// per-tile-local softmax stats, writes P'=exp(S-m_t) bf16 + (m_t, Z_t).
// Fully-masked tiles: stats only (PV skips those panels entirely).
__global__ __launch_bounds__(256, 2) void attn_logits_kernel(
    const unsigned short* __restrict__ Uh, const unsigned short* __restrict__ Ul,
    const unsigned short* __restrict__ Vh, const unsigned short* __restrict__ Vl,
    const int* __restrict__ lengths,
    unsigned short* __restrict__ Pp, float* __restrict__ m_used,
    float* __restrict__ Z_used) {
    __shared__ alignas(16) unsigned short sUh[128 * 32], sUl[128 * 32],
                                          sVh[128 * 32], sVl[128 * 32];
    const int b = blockIdx.z, ut = blockIdx.x, vt = blockIdx.y;
    const int t = threadIdx.x, lane = t & 63, w = t >> 6;
    const int fr = lane & 15, fg = lane >> 4;
    const int length = lengths[b];
    const int row0 = ut * 128, col0 = vt * 128;

    if (col0 >= length) {   // fully-masked tile: degenerate stats only
        if (t < 128) {
            const size_t row = (size_t)b * LU_ + row0 + t;
            m_used[row * NT_ + vt] = -__builtin_inff();
            Z_used[row * NT_ + vt] = 0.f;
        }
        return;
    }

    const int sr0 = w * 16 + (lane >> 2);
    const int sr1 = 64 + sr0;
    const int c0 = (lane & 3) ^ ((sr0 >> 1) & 3);
    const int c1 = (lane & 3) ^ ((sr1 >> 1) & 3);
    const size_t uo0 = ((size_t)b * LU_ + row0 + sr0) * D_ + c0 * 8;
    const size_t uo1 = ((size_t)b * LU_ + row0 + sr1) * D_ + c1 * 8;
    const size_t vo0 = ((size_t)b * LV_ + col0 + sr0) * D_ + c0 * 8;
    const size_t vo1 = ((size_t)b * LV_ + col0 + sr1) * D_ + c1 * 8;
    const int db0 = (w * 16) * 32;
    const int db1 = (64 + w * 16) * 32;

    int aoff[2], boff[8];
#pragma unroll
    for (int m = 0; m < 2; m++) {
        const int r = w * 32 + m * 16 + fr;
        aoff[m] = r * 32 + (fg ^ ((r >> 1) & 3)) * 8;
    }
#pragma unroll
    for (int n = 0; n < 8; n++) {
        const int r = n * 16 + fr;
        boff[n] = r * 32 + (fg ^ ((r >> 1) & 3)) * 8;
    }

    const f32x4 fzero = {0.f, 0.f, 0.f, 0.f};
    f32x4 acc[2][8];
#pragma unroll
    for (int m = 0; m < 2; m++)
#pragma unroll
        for (int n = 0; n < 8; n++) acc[m][n] = fzero;

    for (int k0 = 0; k0 < D_; k0 += 32) {
        __syncthreads();
        gload_lds16(Uh + uo0 + k0, &sUh[db0]);
        gload_lds16(Uh + uo1 + k0, &sUh[db1]);
        gload_lds16(Ul + uo0 + k0, &sUl[db0]);
        gload_lds16(Ul + uo1 + k0, &sUl[db1]);
        gload_lds16(Vh + vo0 + k0, &sVh[db0]);
        gload_lds16(Vh + vo1 + k0, &sVh[db1]);
        gload_lds16(Vl + vo0 + k0, &sVl[db0]);
        gload_lds16(Vl + vo1 + k0, &sVl[db1]);
        __syncthreads();
        const bf16x8 ah0 = *(const bf16x8*)&sUh[aoff[0]];
        const bf16x8 ah1 = *(const bf16x8*)&sUh[aoff[1]];
        const bf16x8 al0 = *(const bf16x8*)&sUl[aoff[0]];
        const bf16x8 al1 = *(const bf16x8*)&sUl[aoff[1]];
#pragma unroll
        for (int n = 0; n < 8; n++) {
            const bf16x8 bh = *(const bf16x8*)&sVh[boff[n]];
            const bf16x8 bl = *(const bf16x8*)&sVl[boff[n]];
            acc[0][n] = __builtin_amdgcn_mfma_f32_16x16x32_bf16(ah0, bh, acc[0][n], 0, 0, 0);
            acc[0][n] = __builtin_amdgcn_mfma_f32_16x16x32_bf16(ah0, bl, acc[0][n], 0, 0, 0);
            acc[0][n] = __builtin_amdgcn_mfma_f32_16x16x32_bf16(al0, bh, acc[0][n], 0, 0, 0);
            acc[1][n] = __builtin_amdgcn_mfma_f32_16x16x32_bf16(ah1, bh, acc[1][n], 0, 0, 0);
            acc[1][n] = __builtin_amdgcn_mfma_f32_16x16x32_bf16(ah1, bl, acc[1][n], 0, 0, 0);
            acc[1][n] = __builtin_amdgcn_mfma_f32_16x16x32_bf16(al1, bh, acc[1][n], 0, 0, 0);
        }
    }

    // per-tile stats: rows are wave-local (wave = 32 rows x 128 cols)
#pragma unroll
    for (int m = 0; m < 2; m++) {
        float mt[4] = {-__builtin_inff(), -__builtin_inff(), -__builtin_inff(), -__builtin_inff()};
#pragma unroll
        for (int n = 0; n < 8; n++) {
            const int col = col0 + n * 16 + fr;
            if (col < length) {
#pragma unroll
                for (int j = 0; j < 4; j++) mt[j] = fmaxf(mt[j], acc[m][n][j]);
            }
        }
#pragma unroll
        for (int d = 1; d < 16; d <<= 1) {
#pragma unroll
            for (int j = 0; j < 4; j++) mt[j] = fmaxf(mt[j], __shfl_xor(mt[j], d));
        }
        float rs[4] = {0.f, 0.f, 0.f, 0.f};
#pragma unroll
        for (int n = 0; n < 8; n++) {
            const int col = col0 + n * 16 + fr;
            const bool valid = (col < length);
#pragma unroll
            for (int j = 0; j < 4; j++) {
                const float p = valid ? __expf(acc[m][n][j] - mt[j]) : 0.f;
                rs[j] += p;
                const size_t row = (size_t)b * LU_ + row0 + w * 32 + m * 16 + fg * 4 + j;
                Pp[row * LV_ + col] = f2bf(p);
            }
        }
#pragma unroll
        for (int d = 1; d < 16; d <<= 1) {
#pragma unroll
            for (int j = 0; j < 4; j++) rs[j] += __shfl_xor(rs[j], d);
        }
        if (fr == 0) {
#pragma unroll
            for (int j = 0; j < 4; j++) {
                const size_t row = (size_t)b * LU_ + row0 + w * 32 + m * 16 + fg * 4 + j;
                m_used[row * NT_ + vt] = mt[j];
                Z_used[row * NT_ + vt] = rs[j];
            }
        }
    }
}

// ---------------------------------------------------------------------------
// K5: combine per-tile stats -> Sc[row][vt] = exp(m_t - m_fin) / Z
__global__ __launch_bounds__(256) void stats_combine_kernel(
    const float* __restrict__ m_used, const float* __restrict__ Z_used,
    float* __restrict__ Sc) {
    const int row = blockIdx.x * 256 + threadIdx.x;
    float mv[NT_];
    float m = -__builtin_inff();
#pragma unroll
    for (int i = 0; i < NT_; i++) {
        mv[i] = m_used[(size_t)row * NT_ + i];
        m = fmaxf(m, mv[i]);
    }
    float ev[NT_];
    float z = 0.f;
#pragma unroll
    for (int i = 0; i < NT_; i++) {
        ev[i] = __expf(mv[i] - m);
        z += Z_used[(size_t)row * NT_ + i] * ev[i];
    }
    const float inv = 1.f / z;
#pragma unroll
    for (int i = 0; i < NT_; i++) Sc[(size_t)row * NT_ + i] = ev[i] * inv;
}

// ---------------------------------------------------------------------------
// K6: out = sum_vt Sc(row,vt) * (P'_vt @ V_vt). 128x128 tile, BK=64,
// 4 waves 2x2 of 64x64, gload_lds + swizzle, scale folded per v-tile.
// Skips fully-masked v-tiles (contribution exactly zero).
__global__ __launch_bounds__(256, 2) void pv_gemm_kernel(
    const unsigned short* __restrict__ Pp, const unsigned short* __restrict__ VT,
    const float* __restrict__ Sc, const int* __restrict__ lengths,
    float* __restrict__ Out) {
    __shared__ alignas(16) unsigned short sA[128 * 64], sB[128 * 64];
    const int b = blockIdx.z, bm = blockIdx.x, bn = blockIdx.y;
    const int t = threadIdx.x, lane = t & 63, w = t >> 6;
    const int wr = (w >> 1) * 64, wc = (w & 1) * 64;
    const int fr = lane & 15, fg = lane >> 4;
    const int length = lengths[b];
    const int ntv = (length + 127) >> 7;   // valid v-tiles (block-uniform)

    // staging: wave w rows [w*32, +32), issue i in {0..3} rows [w*32+i*8, +8)
    size_t aog[4], bog[4];
    int dbs[4];
#pragma unroll
    for (int i = 0; i < 4; i++) {
        const int r = w * 32 + i * 8 + (lane >> 3);
        const int cg = (lane & 7) ^ (r & 7);
        aog[i] = ((size_t)b * LU_ + bm * 128 + r) * LV_ + cg * 8;
        bog[i] = ((size_t)b * D_ + bn * 128 + r) * LV_ + cg * 8;
        dbs[i] = (w * 32 + i * 8) * 64;
    }
    int aoff[2][4], boff[2][4];
#pragma unroll
    for (int kk = 0; kk < 2; kk++) {
#pragma unroll
        for (int m = 0; m < 4; m++) {
            const int r = wr + m * 16 + fr;
            aoff[kk][m] = r * 64 + (((kk * 4 + fg) ^ (r & 7))) * 8;
        }
#pragma unroll
        for (int n = 0; n < 4; n++) {
            const int r = wc + n * 16 + fr;
            boff[kk][n] = r * 64 + (((kk * 4 + fg) ^ (r & 7))) * 8;
        }
    }

    const f32x4 fzero = {0.f, 0.f, 0.f, 0.f};
    f32x4 acc[4][4];
#pragma unroll
    for (int m = 0; m < 4; m++)
#pragma unroll
        for (int n = 0; n < 4; n++) acc[m][n] = fzero;

    const int rowb = bm * 128 + wr + fg * 4;   // + m*16 + j

#pragma unroll 1
    for (int vt = 0; vt < ntv; ++vt) {
        f32x4 part[4][4];
#pragma unroll
        for (int m = 0; m < 4; m++)
#pragma unroll
            for (int n = 0; n < 4; n++) part[m][n] = fzero;

#pragma unroll 1
        for (int kb = 0; kb < 2; ++kb) {
            const int k0 = vt * 128 + kb * 64;
            __syncthreads();
#pragma unroll
            for (int i = 0; i < 4; i++) {
                gload_lds16(Pp + aog[i] + k0, &sA[dbs[i]]);
                gload_lds16(VT + bog[i] + k0, &sB[dbs[i]]);
            }
            __syncthreads();
#pragma unroll
            for (int kk = 0; kk < 2; kk++) {
                bf16x8 af[4];
#pragma unroll
                for (int m = 0; m < 4; m++) af[m] = *(const bf16x8*)&sA[aoff[kk][m]];
#pragma unroll
                for (int n = 0; n < 4; n++) {
                    const bf16x8 bv = *(const bf16x8*)&sB[boff[kk][n]];
#pragma unroll
                    for (int m = 0; m < 4; m++)
                        part[m][n] = __builtin_amdgcn_mfma_f32_16x16x32_bf16(af[m], bv, part[m][n], 0, 0, 0);
                }
            }
        }
        float sc[4][4];
#pragma unroll
        for (int m = 0; m < 4; m++)
#pragma unroll
            for (int j = 0; j < 4; j++)
                sc[m][j] = Sc[((size_t)b * LU_ + rowb + m * 16 + j) * NT_ + vt];
#pragma unroll
        for (int m = 0; m < 4; m++)
#pragma unroll
            for (int n = 0; n < 4; n++)
#pragma unroll
                for (int j = 0; j < 4; j++)
                    acc[m][n][j] += sc[m][j] * part[m][n][j];
    }

    float* Ob = Out + (size_t)b * LU_ * D_;
#pragma unroll
    for (int m = 0; m < 4; m++) {
        const int rbase = bm * 128 + wr + m * 16 + fg * 4;
#pragma unroll
        for (int n = 0; n < 4; n++) {
            const int col = bn * 128 + wc + n * 16 + fr;
#pragma unroll
            for (int j = 0; j < 4; j++)
                Ob[(size_t)(rbase + j) * D_ + col] = acc[m][n][j];
        }
    }
}

// ---------------------------------------------------------------------------
extern "C" void kernel_launch(void* const* d_in, const int* in_sizes, int n_in,
                              void* d_out, int out_size, void* d_ws, size_t ws_size,
                              hipStream_t stream) {
    (void)in_sizes; (void)n_in; (void)out_size; (void)ws_size;
    const float* u    = (const float*)d_in[0];
    const float* v    = (const float*)d_in[1];
    const void*  vm   = d_in[2];
    const float* W    = (const float*)d_in[3];
    const float* bias = (const float*)d_in[4];
    float* out = (float*)d_out;
    char* ws = (char*)d_ws;

    // ws layout (max concurrent ~464 MB; xs region reused by Pp)
    unsigned short* xs_hi = (unsigned short*)(ws + 0 * MB_);      // 64MB (transient)
    unsigned short* xs_lo = (unsigned short*)(ws + 64 * MB_);     // 64MB (transient)
    unsigned short* Pp    = (unsigned short*)(ws + 0 * MB_);      // 128MB (aliases xs)
    unsigned short* vT    = (unsigned short*)(ws + 128 * MB_);    // 64MB
    unsigned short* W_hi  = (unsigned short*)(ws + 192 * MB_);    // 2MB
    unsigned short* W_lo  = (unsigned short*)(ws + 194 * MB_);    // 2MB
    int*   lengths = (int*)(ws + 196 * MB_);
    float* m_used  = (float*)(ws + 197 * MB_);                    // 2MB
    float* Z_used  = (float*)(ws + 199 * MB_);                    // 2MB
    float* Sc      = (float*)(ws + 201 * MB_);                    // 2MB
    unsigned short* u_hi = (unsigned short*)(ws + 208 * MB_);     // 64MB
    unsigned short* u_lo = (unsigned short*)(ws + 272 * MB_);
    unsigned short* v_hi = (unsigned short*)(ws + 336 * MB_);
    unsigned short* v_lo = (unsigned short*)(ws + 400 * MB_);     // end 464MB

    const long nW8 = (long)D_ * D_ / 8;
    const long nX8 = (long)B_ * LU_ * D_ / 8;

    lengths_kernel<<<1, 256, 0, stream>>>(vm, lengths);
    split_kernel<<<512, 256, 0, stream>>>(W, W_hi, W_lo, nW8);
    split_kernel<<<4096, 256, 0, stream>>>(u, xs_hi, xs_lo, nX8);
    proj_kernel<<<dim3(B_ * LU_ / 128, D_ / 128), 256, 0, stream>>>(
        xs_hi, xs_lo, W_hi, W_lo, bias, lengths, 0, u_hi, u_lo);
    split_kernel<<<4096, 256, 0, stream>>>(v, xs_hi, xs_lo, nX8);
    proj_kernel<<<dim3(B_ * LV_ / 128, D_ / 128), 256, 0, stream>>>(
        xs_hi, xs_lo, W_hi, W_lo, bias, lengths, 1, v_hi, v_lo);
    transpose_v_kernel<<<dim3(LV_ / 64, D_ / 64, B_), 256, 0, stream>>>(v, vT);
    attn_logits_kernel<<<dim3(LU_ / 128, NT_, B_), 256, 0, stream>>>(
        u_hi, u_lo, v_hi, v_lo, lengths, Pp, m_used, Z_used);
    stats_combine_kernel<<<B_ * LU_ / 256, 256, 0, stream>>>(m_used, Z_used, Sc);
    pv_gemm_kernel<<<dim3(LU_ / 128, D_ / 128, B_), 256, 0, stream>>>(Pp, vT, Sc, lengths, out);
}

// Round 6
// 666.146 us; speedup vs baseline: 2.0777x; 1.7038x over previous
//
#include <hip/hip_runtime.h>
#include <math.h>

// Problem constants
#define B_  16
#define LU_ 2048
#define LV_ 2048
#define D_  1024
#define NT_ (LV_ / 128)   // 16 v-tiles of 128
#define MB_ (1024ull * 1024ull)

typedef __attribute__((ext_vector_type(8))) short ush8;        // 8 x 16-bit storage
typedef __attribute__((ext_vector_type(8))) _Float16 f16x8;    // MFMA A/B fragment
typedef __attribute__((ext_vector_type(4))) float f32x4;

__device__ __forceinline__ unsigned short f2h(float x) {
    _Float16 h = (_Float16)x;                 // v_cvt_f16_f32, RNE
    return __builtin_bit_cast(unsigned short, h);
}

__device__ __forceinline__ void gload_lds16(const void* g, void* l) {
    __builtin_amdgcn_global_load_lds(
        (const __attribute__((address_space(1))) void*)g,
        (__attribute__((address_space(3))) void*)l, 16, 0, 0);
}

// ---------------------------------------------------------------------------
// K0: per-batch valid length from mask, with byte-vs-int32 layout detection.
__global__ void lengths_kernel(const void* __restrict__ mask, int* __restrict__ lengths) {
    __shared__ int viol;
    __shared__ int cnt[B_];
    const int t = threadIdx.x;
    if (t == 0) viol = 0;
    if (t < B_) cnt[t] = 0;
    __syncthreads();
    const unsigned char* mb = (const unsigned char*)mask;
    int local = 0;
    for (int i = t; i < B_ * LV_ - 1; i += 256) {
        if (((i + 1) % LV_) != 0) {
            if (mb[i] != 0 && mb[i + 1] == 0) local++;
        }
    }
    if (local) atomicAdd(&viol, local);
    __syncthreads();
    const bool is_i32 = (viol > 0);
    const int b = t >> 4, s = t & 15;
    int c = 0;
    if (is_i32) {
        const int* mi = (const int*)mask;
        for (int v2 = s; v2 < LV_; v2 += 16) c += (mi[b * LV_ + v2] == 0) ? 1 : 0;
    } else {
        for (int v2 = s; v2 < LV_; v2 += 16) c += (mb[b * LV_ + v2] == 0) ? 1 : 0;
    }
    atomicAdd(&cnt[b], c);
    __syncthreads();
    if (t < B_) lengths[t] = cnt[t];
}

// ---------------------------------------------------------------------------
// K1: fp32 -> fp16 cast (elementwise, 8 elems/thread, grid-stride)
__global__ __launch_bounds__(256) void cvt_kernel(
    const float* __restrict__ X, unsigned short* __restrict__ Y, long n8) {
    const long stride = (long)gridDim.x * 256;
    for (long i = (long)blockIdx.x * 256 + threadIdx.x; i < n8; i += stride) {
        float4 x0 = ((const float4*)X)[i * 2];
        float4 x1 = ((const float4*)X)[i * 2 + 1];
        float xv[8] = {x0.x, x0.y, x0.z, x0.w, x1.x, x1.y, x1.z, x1.w};
        ush8 h;
#pragma unroll
        for (int j = 0; j < 8; j++) h[j] = (short)f2h(xv[j]);
        ((ush8*)Y)[i] = h;
    }
}

// ---------------------------------------------------------------------------
// K2: Y = relu(X @ W^T + b), all fp16, single-term MFMA GEMM.
// 128x128 tile, BK=32, 4 waves of 32 rows x 128 cols, gload_lds + swizzle.
// is_v != 0: skip row-blocks that are fully masked (lv0 >= lengths[b]).
__global__ __launch_bounds__(256, 2) void proj_kernel(
    const unsigned short* __restrict__ Xf, const unsigned short* __restrict__ Wf,
    const float* __restrict__ bias, const int* __restrict__ lengths, int is_v,
    unsigned short* __restrict__ Yf) {
    if (is_v) {
        const int bb = blockIdx.x >> 4;          // 16 blocks of 128 rows per batch
        const int lv0 = (blockIdx.x & 15) * 128;
        if (lv0 >= lengths[bb]) return;          // fully-masked row block
    }
    __shared__ alignas(16) unsigned short sA[128 * 32], sB[128 * 32];
    const int t = threadIdx.x, lane = t & 63, w = t >> 6;
    const int fr = lane & 15, fg = lane >> 4;
    const int row0 = blockIdx.x * 128, col0 = blockIdx.y * 128;

    // staging geometry (R2-proven): issue i in {0,1} covers rows [i*64+w*16,+16)
    const int sr0 = w * 16 + (lane >> 2);
    const int sr1 = 64 + sr0;
    const int c0 = (lane & 3) ^ ((sr0 >> 1) & 3);
    const int c1 = (lane & 3) ^ ((sr1 >> 1) & 3);
    const size_t ao0 = (size_t)(row0 + sr0) * D_ + c0 * 8;
    const size_t ao1 = (size_t)(row0 + sr1) * D_ + c1 * 8;
    const size_t bo0 = (size_t)(col0 + sr0) * D_ + c0 * 8;
    const size_t bo1 = (size_t)(col0 + sr1) * D_ + c1 * 8;
    const int db0 = (w * 16) * 32;
    const int db1 = (64 + w * 16) * 32;

    // fragment read offsets (swizzled), loop-invariant
    int aoff[2], boff[8];
#pragma unroll
    for (int m = 0; m < 2; m++) {
        const int r = w * 32 + m * 16 + fr;
        aoff[m] = r * 32 + (fg ^ ((r >> 1) & 3)) * 8;
    }
#pragma unroll
    for (int n = 0; n < 8; n++) {
        const int r = n * 16 + fr;
        boff[n] = r * 32 + (fg ^ ((r >> 1) & 3)) * 8;
    }

    const f32x4 fzero = {0.f, 0.f, 0.f, 0.f};
    f32x4 acc[2][8];
#pragma unroll
    for (int m = 0; m < 2; m++)
#pragma unroll
        for (int n = 0; n < 8; n++) acc[m][n] = fzero;

    for (int k0 = 0; k0 < D_; k0 += 32) {
        __syncthreads();
        gload_lds16(Xf + ao0 + k0, &sA[db0]);
        gload_lds16(Xf + ao1 + k0, &sA[db1]);
        gload_lds16(Wf + bo0 + k0, &sB[db0]);
        gload_lds16(Wf + bo1 + k0, &sB[db1]);
        __syncthreads();
        const f16x8 a0 = *(const f16x8*)&sA[aoff[0]];
        const f16x8 a1 = *(const f16x8*)&sA[aoff[1]];
#pragma unroll
        for (int n = 0; n < 8; n++) {
            const f16x8 bv = *(const f16x8*)&sB[boff[n]];
            acc[0][n] = __builtin_amdgcn_mfma_f32_16x16x32_f16(a0, bv, acc[0][n], 0, 0, 0);
            acc[1][n] = __builtin_amdgcn_mfma_f32_16x16x32_f16(a1, bv, acc[1][n], 0, 0, 0);
        }
    }

#pragma unroll
    for (int m = 0; m < 2; m++)
#pragma unroll
        for (int n = 0; n < 8; n++) {
            const int col = col0 + n * 16 + fr;
            const float bv = bias[col];
#pragma unroll
            for (int j = 0; j < 4; j++) {
                const int row = row0 + w * 32 + m * 16 + fg * 4 + j;
                const float y = fmaxf(acc[m][n][j] + bv, 0.f);
                Yf[(size_t)row * D_ + col] = f2h(y);
            }
        }
}

// ---------------------------------------------------------------------------
// K3: v fp32 [B][LV][D] -> vT fp16 [B][D][LV]  AND  vraw fp16 [B][LV][D]
__global__ __launch_bounds__(256) void transpose_v_kernel(
    const float* __restrict__ V, unsigned short* __restrict__ VT,
    unsigned short* __restrict__ Vraw) {
    __shared__ unsigned short s[64 * 72];
    const int b = blockIdx.z;
    const int v0 = blockIdx.x * 64, d0 = blockIdx.y * 64;
    const int t = threadIdx.x;
    {
        const int r = t >> 2, q = (t & 3) * 16;
        const float* src = V + ((size_t)b * LV_ + v0 + r) * D_ + d0 + q;
        unsigned short hb[16];
#pragma unroll
        for (int i = 0; i < 4; i++) {
            float4 x = ((const float4*)src)[i];
            hb[i * 4 + 0] = f2h(x.x);
            hb[i * 4 + 1] = f2h(x.y);
            hb[i * 4 + 2] = f2h(x.z);
            hb[i * 4 + 3] = f2h(x.w);
        }
#pragma unroll
        for (int j = 0; j < 16; j++) s[r * 72 + q + j] = hb[j];
        unsigned short* rdst = Vraw + ((size_t)b * LV_ + v0 + r) * D_ + d0 + q;
        ((ush8*)rdst)[0] = *(ush8*)&hb[0];
        ((ush8*)rdst)[1] = *(ush8*)&hb[8];
    }
    __syncthreads();
    {
        const int d = t >> 2, vq = (t & 3) * 16;
        ush8 t0, t1;
#pragma unroll
        for (int j = 0; j < 8; j++) t0[j] = (short)s[(vq + j) * 72 + d];
#pragma unroll
        for (int j = 0; j < 8; j++) t1[j] = (short)s[(vq + 8 + j) * 72 + d];
        unsigned short* dst = VT + ((size_t)b * D_ + d0 + d) * LV_ + v0 + vq;
        ((ush8*)dst)[0] = t0;
        ((ush8*)dst)[1] = t1;
    }
}

// ---------------------------------------------------------------------------
// K4: logits tile kernel. Grid (LU/128, NT, B). One 128x128 S-tile per WG,
// single fp16 MFMA, per-tile softmax stats, P'=exp(S-m_t) fp16.
// Fully-masked tiles: stats only (PV skips those panels entirely).
__global__ __launch_bounds__(256, 2) void attn_logits_kernel(
    const unsigned short* __restrict__ Uf, const unsigned short* __restrict__ Vf,
    const int* __restrict__ lengths,
    unsigned short* __restrict__ Pp, float* __restrict__ m_used,
    float* __restrict__ Z_used) {
    __shared__ alignas(16) unsigned short sU[128 * 32], sV[128 * 32];
    const int b = blockIdx.z, ut = blockIdx.x, vt = blockIdx.y;
    const int t = threadIdx.x, lane = t & 63, w = t >> 6;
    const int fr = lane & 15, fg = lane >> 4;
    const int length = lengths[b];
    const int row0 = ut * 128, col0 = vt * 128;

    if (col0 >= length) {   // fully-masked tile: degenerate stats only
        if (t < 128) {
            const size_t row = (size_t)b * LU_ + row0 + t;
            m_used[row * NT_ + vt] = -__builtin_inff();
            Z_used[row * NT_ + vt] = 0.f;
        }
        return;
    }

    const int sr0 = w * 16 + (lane >> 2);
    const int sr1 = 64 + sr0;
    const int c0 = (lane & 3) ^ ((sr0 >> 1) & 3);
    const int c1 = (lane & 3) ^ ((sr1 >> 1) & 3);
    const size_t uo0 = ((size_t)b * LU_ + row0 + sr0) * D_ + c0 * 8;
    const size_t uo1 = ((size_t)b * LU_ + row0 + sr1) * D_ + c1 * 8;
    const size_t vo0 = ((size_t)b * LV_ + col0 + sr0) * D_ + c0 * 8;
    const size_t vo1 = ((size_t)b * LV_ + col0 + sr1) * D_ + c1 * 8;
    const int db0 = (w * 16) * 32;
    const int db1 = (64 + w * 16) * 32;

    int aoff[2], boff[8];
#pragma unroll
    for (int m = 0; m < 2; m++) {
        const int r = w * 32 + m * 16 + fr;
        aoff[m] = r * 32 + (fg ^ ((r >> 1) & 3)) * 8;
    }
#pragma unroll
    for (int n = 0; n < 8; n++) {
        const int r = n * 16 + fr;
        boff[n] = r * 32 + (fg ^ ((r >> 1) & 3)) * 8;
    }

    const f32x4 fzero = {0.f, 0.f, 0.f, 0.f};
    f32x4 acc[2][8];
#pragma unroll
    for (int m = 0; m < 2; m++)
#pragma unroll
        for (int n = 0; n < 8; n++) acc[m][n] = fzero;

    for (int k0 = 0; k0 < D_; k0 += 32) {
        __syncthreads();
        gload_lds16(Uf + uo0 + k0, &sU[db0]);
        gload_lds16(Uf + uo1 + k0, &sU[db1]);
        gload_lds16(Vf + vo0 + k0, &sV[db0]);
        gload_lds16(Vf + vo1 + k0, &sV[db1]);
        __syncthreads();
        const f16x8 a0 = *(const f16x8*)&sU[aoff[0]];
        const f16x8 a1 = *(const f16x8*)&sU[aoff[1]];
#pragma unroll
        for (int n = 0; n < 8; n++) {
            const f16x8 bv = *(const f16x8*)&sV[boff[n]];
            acc[0][n] = __builtin_amdgcn_mfma_f32_16x16x32_f16(a0, bv, acc[0][n], 0, 0, 0);
            acc[1][n] = __builtin_amdgcn_mfma_f32_16x16x32_f16(a1, bv, acc[1][n], 0, 0, 0);
        }
    }

    // per-tile stats: rows are wave-local (wave = 32 rows x 128 cols)
#pragma unroll
    for (int m = 0; m < 2; m++) {
        float mt[4] = {-__builtin_inff(), -__builtin_inff(), -__builtin_inff(), -__builtin_inff()};
#pragma unroll
        for (int n = 0; n < 8; n++) {
            const int col = col0 + n * 16 + fr;
            if (col < length) {
#pragma unroll
                for (int j = 0; j < 4; j++) mt[j] = fmaxf(mt[j], acc[m][n][j]);
            }
        }
#pragma unroll
        for (int d = 1; d < 16; d <<= 1) {
#pragma unroll
            for (int j = 0; j < 4; j++) mt[j] = fmaxf(mt[j], __shfl_xor(mt[j], d));
        }
        float rs[4] = {0.f, 0.f, 0.f, 0.f};
#pragma unroll
        for (int n = 0; n < 8; n++) {
            const int col = col0 + n * 16 + fr;
            const bool valid = (col < length);
#pragma unroll
            for (int j = 0; j < 4; j++) {
                const float p = valid ? __expf(acc[m][n][j] - mt[j]) : 0.f;
                rs[j] += p;
                const size_t row = (size_t)b * LU_ + row0 + w * 32 + m * 16 + fg * 4 + j;
                Pp[row * LV_ + col] = f2h(p);
            }
        }
#pragma unroll
        for (int d = 1; d < 16; d <<= 1) {
#pragma unroll
            for (int j = 0; j < 4; j++) rs[j] += __shfl_xor(rs[j], d);
        }
        if (fr == 0) {
#pragma unroll
            for (int j = 0; j < 4; j++) {
                const size_t row = (size_t)b * LU_ + row0 + w * 32 + m * 16 + fg * 4 + j;
                m_used[row * NT_ + vt] = mt[j];
                Z_used[row * NT_ + vt] = rs[j];
            }
        }
    }
}

// ---------------------------------------------------------------------------
// K5: combine per-tile stats -> Sc[row][vt] = exp(m_t - m_fin) / Z
__global__ __launch_bounds__(256) void stats_combine_kernel(
    const float* __restrict__ m_used, const float* __restrict__ Z_used,
    float* __restrict__ Sc) {
    const int row = blockIdx.x * 256 + threadIdx.x;
    float mv[NT_];
    float m = -__builtin_inff();
#pragma unroll
    for (int i = 0; i < NT_; i++) {
        mv[i] = m_used[(size_t)row * NT_ + i];
        m = fmaxf(m, mv[i]);
    }
    float ev[NT_];
    float z = 0.f;
#pragma unroll
    for (int i = 0; i < NT_; i++) {
        ev[i] = __expf(mv[i] - m);
        z += Z_used[(size_t)row * NT_ + i] * ev[i];
    }
    const float inv = 1.f / z;
#pragma unroll
    for (int i = 0; i < NT_; i++) Sc[(size_t)row * NT_ + i] = ev[i] * inv;
}

// ---------------------------------------------------------------------------
// K6: out = sum_vt Sc(row,vt) * (P'_vt @ V_vt). 128x128 tile, BK=64,
// 4 waves 2x2 of 64x64, gload_lds + swizzle, scale folded per v-tile.
// Skips fully-masked v-tiles (contribution exactly zero).
__global__ __launch_bounds__(256, 2) void pv_gemm_kernel(
    const unsigned short* __restrict__ Pp, const unsigned short* __restrict__ VT,
    const float* __restrict__ Sc, const int* __restrict__ lengths,
    float* __restrict__ Out) {
    __shared__ alignas(16) unsigned short sA[128 * 64], sB[128 * 64];
    const int b = blockIdx.z, bm = blockIdx.x, bn = blockIdx.y;
    const int t = threadIdx.x, lane = t & 63, w = t >> 6;
    const int wr = (w >> 1) * 64, wc = (w & 1) * 64;
    const int fr = lane & 15, fg = lane >> 4;
    const int length = lengths[b];
    const int ntv = (length + 127) >> 7;   // valid v-tiles (block-uniform)

    // staging: wave w rows [w*32, +32), issue i in {0..3} rows [w*32+i*8, +8)
    size_t aog[4], bog[4];
    int dbs[4];
#pragma unroll
    for (int i = 0; i < 4; i++) {
        const int r = w * 32 + i * 8 + (lane >> 3);
        const int cg = (lane & 7) ^ (r & 7);
        aog[i] = ((size_t)b * LU_ + bm * 128 + r) * LV_ + cg * 8;
        bog[i] = ((size_t)b * D_ + bn * 128 + r) * LV_ + cg * 8;
        dbs[i] = (w * 32 + i * 8) * 64;
    }
    int aoff[2][4], boff[2][4];
#pragma unroll
    for (int kk = 0; kk < 2; kk++) {
#pragma unroll
        for (int m = 0; m < 4; m++) {
            const int r = wr + m * 16 + fr;
            aoff[kk][m] = r * 64 + (((kk * 4 + fg) ^ (r & 7))) * 8;
        }
#pragma unroll
        for (int n = 0; n < 4; n++) {
            const int r = wc + n * 16 + fr;
            boff[kk][n] = r * 64 + (((kk * 4 + fg) ^ (r & 7))) * 8;
        }
    }

    const f32x4 fzero = {0.f, 0.f, 0.f, 0.f};
    f32x4 acc[4][4];
#pragma unroll
    for (int m = 0; m < 4; m++)
#pragma unroll
        for (int n = 0; n < 4; n++) acc[m][n] = fzero;

    const int rowb = bm * 128 + wr + fg * 4;   // + m*16 + j

#pragma unroll 1
    for (int vt = 0; vt < ntv; ++vt) {
        f32x4 part[4][4];
#pragma unroll
        for (int m = 0; m < 4; m++)
#pragma unroll
            for (int n = 0; n < 4; n++) part[m][n] = fzero;

#pragma unroll 1
        for (int kb = 0; kb < 2; ++kb) {
            const int k0 = vt * 128 + kb * 64;
            __syncthreads();
#pragma unroll
            for (int i = 0; i < 4; i++) {
                gload_lds16(Pp + aog[i] + k0, &sA[dbs[i]]);
                gload_lds16(VT + bog[i] + k0, &sB[dbs[i]]);
            }
            __syncthreads();
#pragma unroll
            for (int kk = 0; kk < 2; kk++) {
                f16x8 af[4];
#pragma unroll
                for (int m = 0; m < 4; m++) af[m] = *(const f16x8*)&sA[aoff[kk][m]];
#pragma unroll
                for (int n = 0; n < 4; n++) {
                    const f16x8 bv = *(const f16x8*)&sB[boff[kk][n]];
#pragma unroll
                    for (int m = 0; m < 4; m++)
                        part[m][n] = __builtin_amdgcn_mfma_f32_16x16x32_f16(af[m], bv, part[m][n], 0, 0, 0);
                }
            }
        }
        float sc[4][4];
#pragma unroll
        for (int m = 0; m < 4; m++)
#pragma unroll
            for (int j = 0; j < 4; j++)
                sc[m][j] = Sc[((size_t)b * LU_ + rowb + m * 16 + j) * NT_ + vt];
#pragma unroll
        for (int m = 0; m < 4; m++)
#pragma unroll
            for (int n = 0; n < 4; n++)
#pragma unroll
                for (int j = 0; j < 4; j++)
                    acc[m][n][j] += sc[m][j] * part[m][n][j];
    }

    float* Ob = Out + (size_t)b * LU_ * D_;
#pragma unroll
    for (int m = 0; m < 4; m++) {
        const int rbase = bm * 128 + wr + m * 16 + fg * 4;
#pragma unroll
        for (int n = 0; n < 4; n++) {
            const int col = bn * 128 + wc + n * 16 + fr;
#pragma unroll
            for (int j = 0; j < 4; j++)
                Ob[(size_t)(rbase + j) * D_ + col] = acc[m][n][j];
        }
    }
}

// ---------------------------------------------------------------------------
extern "C" void kernel_launch(void* const* d_in, const int* in_sizes, int n_in,
                              void* d_out, int out_size, void* d_ws, size_t ws_size,
                              hipStream_t stream) {
    (void)in_sizes; (void)n_in; (void)out_size; (void)ws_size;
    const float* u    = (const float*)d_in[0];
    const float* v    = (const float*)d_in[1];
    const void*  vm   = d_in[2];
    const float* W    = (const float*)d_in[3];
    const float* bias = (const float*)d_in[4];
    float* out = (float*)d_out;
    char* ws = (char*)d_ws;

    // ws layout (~457 MB)
    unsigned short* Pp    = (unsigned short*)(ws + 0 * MB_);     // 128MB fp16
    unsigned short* vT    = (unsigned short*)(ws + 128 * MB_);   // 64MB fp16
    unsigned short* u_f   = (unsigned short*)(ws + 192 * MB_);   // 64MB u_ fp16
    unsigned short* v_f   = (unsigned short*)(ws + 256 * MB_);   // 64MB v_ fp16
    unsigned short* vraw  = (unsigned short*)(ws + 320 * MB_);   // 64MB raw v fp16
    unsigned short* xs_u  = (unsigned short*)(ws + 384 * MB_);   // 64MB raw u fp16
    unsigned short* W_f   = (unsigned short*)(ws + 448 * MB_);   // 2MB
    int*   lengths = (int*)(ws + 450 * MB_);
    float* m_used  = (float*)(ws + 451 * MB_);                   // 2MB
    float* Z_used  = (float*)(ws + 453 * MB_);                   // 2MB
    float* Sc      = (float*)(ws + 455 * MB_);                   // 2MB

    const long nW8 = (long)D_ * D_ / 8;
    const long nX8 = (long)B_ * LU_ * D_ / 8;

    lengths_kernel<<<1, 256, 0, stream>>>(vm, lengths);
    cvt_kernel<<<512, 256, 0, stream>>>(W, W_f, nW8);
    cvt_kernel<<<4096, 256, 0, stream>>>(u, xs_u, nX8);
    proj_kernel<<<dim3(B_ * LU_ / 128, D_ / 128), 256, 0, stream>>>(
        xs_u, W_f, bias, lengths, 0, u_f);
    transpose_v_kernel<<<dim3(LV_ / 64, D_ / 64, B_), 256, 0, stream>>>(v, vT, vraw);
    proj_kernel<<<dim3(B_ * LV_ / 128, D_ / 128), 256, 0, stream>>>(
        vraw, W_f, bias, lengths, 1, v_f);
    attn_logits_kernel<<<dim3(LU_ / 128, NT_, B_), 256, 0, stream>>>(
        u_f, v_f, lengths, Pp, m_used, Z_used);
    stats_combine_kernel<<<B_ * LU_ / 256, 256, 0, stream>>>(m_used, Z_used, Sc);
    pv_gemm_kernel<<<dim3(LU_ / 128, D_ / 128, B_), 256, 0, stream>>>(Pp, vT, Sc, lengths, out);
}

// Round 8
// 613.201 us; speedup vs baseline: 2.2571x; 1.0863x over previous
//
#include <hip/hip_runtime.h>
#include <math.h>

// Problem constants
#define B_  16
#define LU_ 2048
#define LV_ 2048
#define D_  1024
#define NT_ (LV_ / 128)   // 16 v-tiles of 128
#define MB_ (1024ull * 1024ull)

typedef __attribute__((ext_vector_type(8))) short ush8;        // 8 x 16-bit storage
typedef __attribute__((ext_vector_type(8))) _Float16 f16x8;    // MFMA A/B fragment
typedef __attribute__((ext_vector_type(4))) float f32x4;

__device__ __forceinline__ unsigned short f2h(float x) {
    _Float16 h = (_Float16)x;                 // v_cvt_f16_f32, RNE
    return __builtin_bit_cast(unsigned short, h);
}

__device__ __forceinline__ void gload_lds16(const void* g, void* l) {
    __builtin_amdgcn_global_load_lds(
        (const __attribute__((address_space(1))) void*)g,
        (__attribute__((address_space(3))) void*)l, 16, 0, 0);
}

// ---------------------------------------------------------------------------
// K0: per-batch valid length from mask, with byte-vs-int32 layout detection.
__global__ void lengths_kernel(const void* __restrict__ mask, int* __restrict__ lengths) {
    __shared__ int viol;
    __shared__ int cnt[B_];
    const int t = threadIdx.x;
    if (t == 0) viol = 0;
    if (t < B_) cnt[t] = 0;
    __syncthreads();
    const unsigned char* mb = (const unsigned char*)mask;
    int local = 0;
    for (int i = t; i < B_ * LV_ - 1; i += 256) {
        if (((i + 1) % LV_) != 0) {
            if (mb[i] != 0 && mb[i + 1] == 0) local++;
        }
    }
    if (local) atomicAdd(&viol, local);
    __syncthreads();
    const bool is_i32 = (viol > 0);
    const int b = t >> 4, s = t & 15;
    int c = 0;
    if (is_i32) {
        const int* mi = (const int*)mask;
        for (int v2 = s; v2 < LV_; v2 += 16) c += (mi[b * LV_ + v2] == 0) ? 1 : 0;
    } else {
        for (int v2 = s; v2 < LV_; v2 += 16) c += (mb[b * LV_ + v2] == 0) ? 1 : 0;
    }
    atomicAdd(&cnt[b], c);
    __syncthreads();
    if (t < B_) lengths[t] = cnt[t];
}

// ---------------------------------------------------------------------------
// K1: fp32 -> fp16 cast (elementwise, 8 elems/thread, grid-stride)
__global__ __launch_bounds__(256) void cvt_kernel(
    const float* __restrict__ X, unsigned short* __restrict__ Y, long n8) {
    const long stride = (long)gridDim.x * 256;
    for (long i = (long)blockIdx.x * 256 + threadIdx.x; i < n8; i += stride) {
        float4 x0 = ((const float4*)X)[i * 2];
        float4 x1 = ((const float4*)X)[i * 2 + 1];
        float xv[8] = {x0.x, x0.y, x0.z, x0.w, x1.x, x1.y, x1.z, x1.w};
        ush8 h;
#pragma unroll
        for (int j = 0; j < 8; j++) h[j] = (short)f2h(xv[j]);
        ((ush8*)Y)[i] = h;
    }
}

// ---------------------------------------------------------------------------
// K2: Y = relu(X @ W^T + b), all fp16, single-term MFMA GEMM.
// 128x128 tile, BK=32, 4 waves of 32 rows x 128 cols, gload_lds + swizzle.
// is_v != 0: skip row-blocks that are fully masked (lv0 >= lengths[b]).
__global__ __launch_bounds__(256, 2) void proj_kernel(
    const unsigned short* __restrict__ Xf, const unsigned short* __restrict__ Wf,
    const float* __restrict__ bias, const int* __restrict__ lengths, int is_v,
    unsigned short* __restrict__ Yf) {
    if (is_v) {
        const int bb = blockIdx.x >> 4;          // 16 blocks of 128 rows per batch
        const int lv0 = (blockIdx.x & 15) * 128;
        if (lv0 >= lengths[bb]) return;          // fully-masked row block
    }
    __shared__ alignas(16) unsigned short sA[128 * 32], sB[128 * 32];
    const int t = threadIdx.x, lane = t & 63, w = t >> 6;
    const int fr = lane & 15, fg = lane >> 4;
    const int row0 = blockIdx.x * 128, col0 = blockIdx.y * 128;

    // staging geometry (R2-proven): issue i in {0,1} covers rows [i*64+w*16,+16)
    const int sr0 = w * 16 + (lane >> 2);
    const int sr1 = 64 + sr0;
    const int c0 = (lane & 3) ^ ((sr0 >> 1) & 3);
    const int c1 = (lane & 3) ^ ((sr1 >> 1) & 3);
    const size_t ao0 = (size_t)(row0 + sr0) * D_ + c0 * 8;
    const size_t ao1 = (size_t)(row0 + sr1) * D_ + c1 * 8;
    const size_t bo0 = (size_t)(col0 + sr0) * D_ + c0 * 8;
    const size_t bo1 = (size_t)(col0 + sr1) * D_ + c1 * 8;
    const int db0 = (w * 16) * 32;
    const int db1 = (64 + w * 16) * 32;

    // fragment read offsets (swizzled), loop-invariant
    int aoff[2], boff[8];
#pragma unroll
    for (int m = 0; m < 2; m++) {
        const int r = w * 32 + m * 16 + fr;
        aoff[m] = r * 32 + (fg ^ ((r >> 1) & 3)) * 8;
    }
#pragma unroll
    for (int n = 0; n < 8; n++) {
        const int r = n * 16 + fr;
        boff[n] = r * 32 + (fg ^ ((r >> 1) & 3)) * 8;
    }

    const f32x4 fzero = {0.f, 0.f, 0.f, 0.f};
    f32x4 acc[2][8];
#pragma unroll
    for (int m = 0; m < 2; m++)
#pragma unroll
        for (int n = 0; n < 8; n++) acc[m][n] = fzero;

    for (int k0 = 0; k0 < D_; k0 += 32) {
        __syncthreads();
        gload_lds16(Xf + ao0 + k0, &sA[db0]);
        gload_lds16(Xf + ao1 + k0, &sA[db1]);
        gload_lds16(Wf + bo0 + k0, &sB[db0]);
        gload_lds16(Wf + bo1 + k0, &sB[db1]);
        __syncthreads();
        const f16x8 a0 = *(const f16x8*)&sA[aoff[0]];
        const f16x8 a1 = *(const f16x8*)&sA[aoff[1]];
#pragma unroll
        for (int n = 0; n < 8; n++) {
            const f16x8 bv = *(const f16x8*)&sB[boff[n]];
            acc[0][n] = __builtin_amdgcn_mfma_f32_16x16x32_f16(a0, bv, acc[0][n], 0, 0, 0);
            acc[1][n] = __builtin_amdgcn_mfma_f32_16x16x32_f16(a1, bv, acc[1][n], 0, 0, 0);
        }
    }

#pragma unroll
    for (int m = 0; m < 2; m++)
#pragma unroll
        for (int n = 0; n < 8; n++) {
            const int col = col0 + n * 16 + fr;
            const float bv = bias[col];
#pragma unroll
            for (int j = 0; j < 4; j++) {
                const int row = row0 + w * 32 + m * 16 + fg * 4 + j;
                const float y = fmaxf(acc[m][n][j] + bv, 0.f);
                Yf[(size_t)row * D_ + col] = f2h(y);
            }
        }
}

// ---------------------------------------------------------------------------
// K3: v fp32 [B][LV][D] -> vT fp16 [B][D][LV]  AND  vraw fp16 [B][LV][D]
__global__ __launch_bounds__(256) void transpose_v_kernel(
    const float* __restrict__ V, unsigned short* __restrict__ VT,
    unsigned short* __restrict__ Vraw) {
    __shared__ unsigned short s[64 * 72];
    const int b = blockIdx.z;
    const int v0 = blockIdx.x * 64, d0 = blockIdx.y * 64;
    const int t = threadIdx.x;
    {
        const int r = t >> 2, q = (t & 3) * 16;
        const float* src = V + ((size_t)b * LV_ + v0 + r) * D_ + d0 + q;
        unsigned short hb[16];
#pragma unroll
        for (int i = 0; i < 4; i++) {
            float4 x = ((const float4*)src)[i];
            hb[i * 4 + 0] = f2h(x.x);
            hb[i * 4 + 1] = f2h(x.y);
            hb[i * 4 + 2] = f2h(x.z);
            hb[i * 4 + 3] = f2h(x.w);
        }
#pragma unroll
        for (int j = 0; j < 16; j++) s[r * 72 + q + j] = hb[j];
        unsigned short* rdst = Vraw + ((size_t)b * LV_ + v0 + r) * D_ + d0 + q;
        ((ush8*)rdst)[0] = *(ush8*)&hb[0];
        ((ush8*)rdst)[1] = *(ush8*)&hb[8];
    }
    __syncthreads();
    {
        const int d = t >> 2, vq = (t & 3) * 16;
        ush8 t0, t1;
#pragma unroll
        for (int j = 0; j < 8; j++) t0[j] = (short)s[(vq + j) * 72 + d];
#pragma unroll
        for (int j = 0; j < 8; j++) t1[j] = (short)s[(vq + 8 + j) * 72 + d];
        unsigned short* dst = VT + ((size_t)b * D_ + d0 + d) * LV_ + v0 + vq;
        ((ush8*)dst)[0] = t0;
        ((ush8*)dst)[1] = t1;
    }
}

// ---------------------------------------------------------------------------
// K4: logits tile kernel. Grid (LU/128, NT, B). One 128x128 S-tile per WG,
// single fp16 MFMA, per-tile softmax stats, P'=exp(S-m_t) fp16.
// Fully-masked tiles: stats only (PV skips those panels entirely).
__global__ __launch_bounds__(256, 2) void attn_logits_kernel(
    const unsigned short* __restrict__ Uf, const unsigned short* __restrict__ Vf,
    const int* __restrict__ lengths,
    unsigned short* __restrict__ Pp, float* __restrict__ m_used,
    float* __restrict__ Z_used) {
    __shared__ alignas(16) unsigned short sU[128 * 32], sV[128 * 32];
    const int b = blockIdx.z, ut = blockIdx.x, vt = blockIdx.y;
    const int t = threadIdx.x, lane = t & 63, w = t >> 6;
    const int fr = lane & 15, fg = lane >> 4;
    const int length = lengths[b];
    const int row0 = ut * 128, col0 = vt * 128;

    if (col0 >= length) {   // fully-masked tile: degenerate stats only
        if (t < 128) {
            const size_t row = (size_t)b * LU_ + row0 + t;
            m_used[row * NT_ + vt] = -__builtin_inff();
            Z_used[row * NT_ + vt] = 0.f;
        }
        return;
    }

    const int sr0 = w * 16 + (lane >> 2);
    const int sr1 = 64 + sr0;
    const int c0 = (lane & 3) ^ ((sr0 >> 1) & 3);
    const int c1 = (lane & 3) ^ ((sr1 >> 1) & 3);
    const size_t uo0 = ((size_t)b * LU_ + row0 + sr0) * D_ + c0 * 8;
    const size_t uo1 = ((size_t)b * LU_ + row0 + sr1) * D_ + c1 * 8;
    const size_t vo0 = ((size_t)b * LV_ + col0 + sr0) * D_ + c0 * 8;
    const size_t vo1 = ((size_t)b * LV_ + col0 + sr1) * D_ + c1 * 8;
    const int db0 = (w * 16) * 32;
    const int db1 = (64 + w * 16) * 32;

    int aoff[2], boff[8];
#pragma unroll
    for (int m = 0; m < 2; m++) {
        const int r = w * 32 + m * 16 + fr;
        aoff[m] = r * 32 + (fg ^ ((r >> 1) & 3)) * 8;
    }
#pragma unroll
    for (int n = 0; n < 8; n++) {
        const int r = n * 16 + fr;
        boff[n] = r * 32 + (fg ^ ((r >> 1) & 3)) * 8;
    }

    const f32x4 fzero = {0.f, 0.f, 0.f, 0.f};
    f32x4 acc[2][8];
#pragma unroll
    for (int m = 0; m < 2; m++)
#pragma unroll
        for (int n = 0; n < 8; n++) acc[m][n] = fzero;

    for (int k0 = 0; k0 < D_; k0 += 32) {
        __syncthreads();
        gload_lds16(Uf + uo0 + k0, &sU[db0]);
        gload_lds16(Uf + uo1 + k0, &sU[db1]);
        gload_lds16(Vf + vo0 + k0, &sV[db0]);
        gload_lds16(Vf + vo1 + k0, &sV[db1]);
        __syncthreads();
        const f16x8 a0 = *(const f16x8*)&sU[aoff[0]];
        const f16x8 a1 = *(const f16x8*)&sU[aoff[1]];
#pragma unroll
        for (int n = 0; n < 8; n++) {
            const f16x8 bv = *(const f16x8*)&sV[boff[n]];
            acc[0][n] = __builtin_amdgcn_mfma_f32_16x16x32_f16(a0, bv, acc[0][n], 0, 0, 0);
            acc[1][n] = __builtin_amdgcn_mfma_f32_16x16x32_f16(a1, bv, acc[1][n], 0, 0, 0);
        }
    }

    // per-tile stats: rows are wave-local (wave = 32 rows x 128 cols)
#pragma unroll
    for (int m = 0; m < 2; m++) {
        float mt[4] = {-__builtin_inff(), -__builtin_inff(), -__builtin_inff(), -__builtin_inff()};
#pragma unroll
        for (int n = 0; n < 8; n++) {
            const int col = col0 + n * 16 + fr;
            if (col < length) {
#pragma unroll
                for (int j = 0; j < 4; j++) mt[j] = fmaxf(mt[j], acc[m][n][j]);
            }
        }
#pragma unroll
        for (int d = 1; d < 16; d <<= 1) {
#pragma unroll
            for (int j = 0; j < 4; j++) mt[j] = fmaxf(mt[j], __shfl_xor(mt[j], d));
        }
        float rs[4] = {0.f, 0.f, 0.f, 0.f};
#pragma unroll
        for (int n = 0; n < 8; n++) {
            const int col = col0 + n * 16 + fr;
            const bool valid = (col < length);
#pragma unroll
            for (int j = 0; j < 4; j++) {
                const float p = valid ? __expf(acc[m][n][j] - mt[j]) : 0.f;
                rs[j] += p;
                const size_t row = (size_t)b * LU_ + row0 + w * 32 + m * 16 + fg * 4 + j;
                Pp[row * LV_ + col] = f2h(p);
            }
        }
#pragma unroll
        for (int d = 1; d < 16; d <<= 1) {
#pragma unroll
            for (int j = 0; j < 4; j++) rs[j] += __shfl_xor(rs[j], d);
        }
        if (fr == 0) {
#pragma unroll
            for (int j = 0; j < 4; j++) {
                const size_t row = (size_t)b * LU_ + row0 + w * 32 + m * 16 + fg * 4 + j;
                m_used[row * NT_ + vt] = mt[j];
                Z_used[row * NT_ + vt] = rs[j];
            }
        }
    }
}

// ---------------------------------------------------------------------------
// K5: combine per-tile stats -> Sc[row][vt] = exp(m_t - m_fin) / Z
__global__ __launch_bounds__(256) void stats_combine_kernel(
    const float* __restrict__ m_used, const float* __restrict__ Z_used,
    float* __restrict__ Sc) {
    const int row = blockIdx.x * 256 + threadIdx.x;
    float mv[NT_];
    float m = -__builtin_inff();
#pragma unroll
    for (int i = 0; i < NT_; i++) {
        mv[i] = m_used[(size_t)row * NT_ + i];
        m = fmaxf(m, mv[i]);
    }
    float ev[NT_];
    float z = 0.f;
#pragma unroll
    for (int i = 0; i < NT_; i++) {
        ev[i] = __expf(mv[i] - m);
        z += Z_used[(size_t)row * NT_ + i] * ev[i];
    }
    const float inv = 1.f / z;
#pragma unroll
    for (int i = 0; i < NT_; i++) Sc[(size_t)row * NT_ + i] = ev[i] * inv;
}

// ---------------------------------------------------------------------------
// K6: out = sum_vt (Sc(row,vt)*P'_vt) @ V_vt. 128x128 tile, BK=64,
// 4 waves 2x2 of 64x64, gload_lds + swizzle.
// Scale applied to the A-FRAGMENT (per-row, f16 pk-mul) -> direct MFMA
// accumulation, no part[]/fold. Sc panel preloaded to LDS (barrier before use!).
// Skips fully-masked v-tiles (contribution exactly zero).
__global__ __launch_bounds__(256, 4) void pv_gemm_kernel(
    const unsigned short* __restrict__ Pp, const unsigned short* __restrict__ VT,
    const float* __restrict__ Sc, const int* __restrict__ lengths,
    float* __restrict__ Out) {
    __shared__ alignas(16) unsigned short sA[128 * 64], sB[128 * 64];
    __shared__ float sSc[128 * NT_];
    const int b = blockIdx.z, bm = blockIdx.x, bn = blockIdx.y;
    const int t = threadIdx.x, lane = t & 63, w = t >> 6;
    const int wr = (w >> 1) * 64, wc = (w & 1) * 64;
    const int fr = lane & 15, fg = lane >> 4;
    const int length = lengths[b];
    const int ntv = (length + 127) >> 7;   // valid v-tiles (block-uniform)

    // preload this row-block's Sc panel: 128 rows x NT floats = 8 KB
    {
        const float* scg = Sc + ((size_t)b * LU_ + bm * 128) * NT_;
#pragma unroll
        for (int i = 0; i < (128 * NT_) / 256; i++)
            sSc[i * 256 + t] = scg[i * 256 + t];
    }
    __syncthreads();   // sSc is read cross-thread below (R7 bug: this was missing)

    // staging: wave w rows [w*32, +32), issue i in {0..3} rows [w*32+i*8, +8)
    size_t aog[4], bog[4];
    int dbs[4];
#pragma unroll
    for (int i = 0; i < 4; i++) {
        const int r = w * 32 + i * 8 + (lane >> 3);
        const int cg = (lane & 7) ^ (r & 7);
        aog[i] = ((size_t)b * LU_ + bm * 128 + r) * LV_ + cg * 8;
        bog[i] = ((size_t)b * D_ + bn * 128 + r) * LV_ + cg * 8;
        dbs[i] = (w * 32 + i * 8) * 64;
    }
    int aoff[2][4], boff[2][4];
#pragma unroll
    for (int kk = 0; kk < 2; kk++) {
#pragma unroll
        for (int m = 0; m < 4; m++) {
            const int r = wr + m * 16 + fr;
            aoff[kk][m] = r * 64 + (((kk * 4 + fg) ^ (r & 7))) * 8;
        }
#pragma unroll
        for (int n = 0; n < 4; n++) {
            const int r = wc + n * 16 + fr;
            boff[kk][n] = r * 64 + (((kk * 4 + fg) ^ (r & 7))) * 8;
        }
    }

    const f32x4 fzero = {0.f, 0.f, 0.f, 0.f};
    f32x4 acc[4][4];
#pragma unroll
    for (int m = 0; m < 4; m++)
#pragma unroll
        for (int n = 0; n < 4; n++) acc[m][n] = fzero;

#pragma unroll 1
    for (int vt = 0; vt < ntv; ++vt) {
        // per-row scale for this v-tile, as f16 splat (A-fragment row = wr+m*16+fr)
        f16x8 scv[4];
#pragma unroll
        for (int m = 0; m < 4; m++) {
            const _Float16 sh = (_Float16)sSc[(wr + m * 16 + fr) * NT_ + vt];
#pragma unroll
            for (int j = 0; j < 8; j++) scv[m][j] = sh;
        }

#pragma unroll 1
        for (int kb = 0; kb < 2; ++kb) {
            const int k0 = vt * 128 + kb * 64;
            __syncthreads();
#pragma unroll
            for (int i = 0; i < 4; i++) {
                gload_lds16(Pp + aog[i] + k0, &sA[dbs[i]]);
                gload_lds16(VT + bog[i] + k0, &sB[dbs[i]]);
            }
            __syncthreads();
#pragma unroll
            for (int kk = 0; kk < 2; kk++) {
                f16x8 af[4];
#pragma unroll
                for (int m = 0; m < 4; m++)
                    af[m] = (*(const f16x8*)&sA[aoff[kk][m]]) * scv[m];
#pragma unroll
                for (int n = 0; n < 4; n++) {
                    const f16x8 bv = *(const f16x8*)&sB[boff[kk][n]];
#pragma unroll
                    for (int m = 0; m < 4; m++)
                        acc[m][n] = __builtin_amdgcn_mfma_f32_16x16x32_f16(af[m], bv, acc[m][n], 0, 0, 0);
                }
            }
        }
    }

    float* Ob = Out + (size_t)b * LU_ * D_;
#pragma unroll
    for (int m = 0; m < 4; m++) {
        const int rbase = bm * 128 + wr + m * 16 + fg * 4;
#pragma unroll
        for (int n = 0; n < 4; n++) {
            const int col = bn * 128 + wc + n * 16 + fr;
#pragma unroll
            for (int j = 0; j < 4; j++)
                Ob[(size_t)(rbase + j) * D_ + col] = acc[m][n][j];
        }
    }
}

// ---------------------------------------------------------------------------
extern "C" void kernel_launch(void* const* d_in, const int* in_sizes, int n_in,
                              void* d_out, int out_size, void* d_ws, size_t ws_size,
                              hipStream_t stream) {
    (void)in_sizes; (void)n_in; (void)out_size; (void)ws_size;
    const float* u    = (const float*)d_in[0];
    const float* v    = (const float*)d_in[1];
    const void*  vm   = d_in[2];
    const float* W    = (const float*)d_in[3];
    const float* bias = (const float*)d_in[4];
    float* out = (float*)d_out;
    char* ws = (char*)d_ws;

    // ws layout (~457 MB)
    unsigned short* Pp    = (unsigned short*)(ws + 0 * MB_);     // 128MB fp16
    unsigned short* vT    = (unsigned short*)(ws + 128 * MB_);   // 64MB fp16
    unsigned short* u_f   = (unsigned short*)(ws + 192 * MB_);   // 64MB u_ fp16
    unsigned short* v_f   = (unsigned short*)(ws + 256 * MB_);   // 64MB v_ fp16
    unsigned short* vraw  = (unsigned short*)(ws + 320 * MB_);   // 64MB raw v fp16
    unsigned short* xs_u  = (unsigned short*)(ws + 384 * MB_);   // 64MB raw u fp16
    unsigned short* W_f   = (unsigned short*)(ws + 448 * MB_);   // 2MB
    int*   lengths = (int*)(ws + 450 * MB_);
    float* m_used  = (float*)(ws + 451 * MB_);                   // 2MB
    float* Z_used  = (float*)(ws + 453 * MB_);                   // 2MB
    float* Sc      = (float*)(ws + 455 * MB_);                   // 2MB

    const long nW8 = (long)D_ * D_ / 8;
    const long nX8 = (long)B_ * LU_ * D_ / 8;

    lengths_kernel<<<1, 256, 0, stream>>>(vm, lengths);
    cvt_kernel<<<512, 256, 0, stream>>>(W, W_f, nW8);
    cvt_kernel<<<4096, 256, 0, stream>>>(u, xs_u, nX8);
    proj_kernel<<<dim3(B_ * LU_ / 128, D_ / 128), 256, 0, stream>>>(
        xs_u, W_f, bias, lengths, 0, u_f);
    transpose_v_kernel<<<dim3(LV_ / 64, D_ / 64, B_), 256, 0, stream>>>(v, vT, vraw);
    proj_kernel<<<dim3(B_ * LV_ / 128, D_ / 128), 256, 0, stream>>>(
        vraw, W_f, bias, lengths, 1, v_f);
    attn_logits_kernel<<<dim3(LU_ / 128, NT_, B_), 256, 0, stream>>>(
        u_f, v_f, lengths, Pp, m_used, Z_used);
    stats_combine_kernel<<<B_ * LU_ / 256, 256, 0, stream>>>(m_used, Z_used, Sc);
    pv_gemm_kernel<<<dim3(LU_ / 128, D_ / 128, B_), 256, 0, stream>>>(Pp, vT, Sc, lengths, out);
}

// Round 9
// 588.809 us; speedup vs baseline: 2.3506x; 1.0414x over previous
//
#include <hip/hip_runtime.h>
#include <math.h>

// Problem constants
#define B_  16
#define LU_ 2048
#define LV_ 2048
#define D_  1024
#define NT_ (LV_ / 128)   // 16 v-tiles of 128
#define MB_ (1024ull * 1024ull)

typedef __attribute__((ext_vector_type(8))) short ush8;        // 8 x 16-bit storage
typedef __attribute__((ext_vector_type(8))) _Float16 f16x8;    // MFMA A/B fragment
typedef __attribute__((ext_vector_type(4))) float f32x4;

__device__ __forceinline__ unsigned short f2h(float x) {
    _Float16 h = (_Float16)x;                 // v_cvt_f16_f32, RNE
    return __builtin_bit_cast(unsigned short, h);
}

__device__ __forceinline__ void gload_lds16(const void* g, void* l) {
    __builtin_amdgcn_global_load_lds(
        (const __attribute__((address_space(1))) void*)g,
        (__attribute__((address_space(3))) void*)l, 16, 0, 0);
}

// ---------------------------------------------------------------------------
// K0: per-batch valid length from mask, with byte-vs-int32 layout detection.
__global__ void lengths_kernel(const void* __restrict__ mask, int* __restrict__ lengths) {
    __shared__ int viol;
    __shared__ int cnt[B_];
    const int t = threadIdx.x;
    if (t == 0) viol = 0;
    if (t < B_) cnt[t] = 0;
    __syncthreads();
    const unsigned char* mb = (const unsigned char*)mask;
    int local = 0;
    for (int i = t; i < B_ * LV_ - 1; i += 256) {
        if (((i + 1) % LV_) != 0) {
            if (mb[i] != 0 && mb[i + 1] == 0) local++;
        }
    }
    if (local) atomicAdd(&viol, local);
    __syncthreads();
    const bool is_i32 = (viol > 0);
    const int b = t >> 4, s = t & 15;
    int c = 0;
    if (is_i32) {
        const int* mi = (const int*)mask;
        for (int v2 = s; v2 < LV_; v2 += 16) c += (mi[b * LV_ + v2] == 0) ? 1 : 0;
    } else {
        for (int v2 = s; v2 < LV_; v2 += 16) c += (mb[b * LV_ + v2] == 0) ? 1 : 0;
    }
    atomicAdd(&cnt[b], c);
    __syncthreads();
    if (t < B_) lengths[t] = cnt[t];
}

// ---------------------------------------------------------------------------
// K1: fp32 -> fp16 cast (elementwise, 8 elems/thread, grid-stride)
__global__ __launch_bounds__(256) void cvt_kernel(
    const float* __restrict__ X, unsigned short* __restrict__ Y, long n8) {
    const long stride = (long)gridDim.x * 256;
    for (long i = (long)blockIdx.x * 256 + threadIdx.x; i < n8; i += stride) {
        float4 x0 = ((const float4*)X)[i * 2];
        float4 x1 = ((const float4*)X)[i * 2 + 1];
        float xv[8] = {x0.x, x0.y, x0.z, x0.w, x1.x, x1.y, x1.z, x1.w};
        ush8 h;
#pragma unroll
        for (int j = 0; j < 8; j++) h[j] = (short)f2h(xv[j]);
        ((ush8*)Y)[i] = h;
    }
}

// ---------------------------------------------------------------------------
// K2: Y = relu(X @ W^T + b), all fp16, single-term MFMA GEMM.
// 128x128 tile, BK=64 (PV-proven staging/swizzle), 4 waves of 32 rows x 128 cols.
// is_v != 0: skip row-blocks that are fully masked (lv0 >= lengths[b]).
__global__ __launch_bounds__(256, 2) void proj_kernel(
    const unsigned short* __restrict__ Xf, const unsigned short* __restrict__ Wf,
    const float* __restrict__ bias, const int* __restrict__ lengths, int is_v,
    unsigned short* __restrict__ Yf) {
    if (is_v) {
        const int bb = blockIdx.x >> 4;          // 16 blocks of 128 rows per batch
        const int lv0 = (blockIdx.x & 15) * 128;
        if (lv0 >= lengths[bb]) return;          // fully-masked row block
    }
    __shared__ alignas(16) unsigned short sA[128 * 64], sB[128 * 64];
    const int t = threadIdx.x, lane = t & 63, w = t >> 6;
    const int fr = lane & 15, fg = lane >> 4;
    const int row0 = blockIdx.x * 128, col0 = blockIdx.y * 128;

    // staging (PV-proven): wave w rows [w*32,+32), issue i rows [w*32+i*8,+8)
    size_t aog[4], bog[4];
    int dbs[4];
#pragma unroll
    for (int i = 0; i < 4; i++) {
        const int r = w * 32 + i * 8 + (lane >> 3);
        const int cg = (lane & 7) ^ (r & 7);
        aog[i] = (size_t)(row0 + r) * D_ + cg * 8;
        bog[i] = (size_t)(col0 + r) * D_ + cg * 8;
        dbs[i] = (w * 32 + i * 8) * 64;
    }
    // fragment read offsets (PV-proven swizzle family)
    int aoff[2][2], boff[2][8];
#pragma unroll
    for (int kk = 0; kk < 2; kk++) {
#pragma unroll
        for (int m = 0; m < 2; m++) {
            const int r = w * 32 + m * 16 + fr;
            aoff[kk][m] = r * 64 + (((kk * 4 + fg) ^ (r & 7))) * 8;
        }
#pragma unroll
        for (int n = 0; n < 8; n++) {
            const int r = n * 16 + fr;
            boff[kk][n] = r * 64 + (((kk * 4 + fg) ^ (r & 7))) * 8;
        }
    }

    const f32x4 fzero = {0.f, 0.f, 0.f, 0.f};
    f32x4 acc[2][8];
#pragma unroll
    for (int m = 0; m < 2; m++)
#pragma unroll
        for (int n = 0; n < 8; n++) acc[m][n] = fzero;

#pragma unroll 1
    for (int k0 = 0; k0 < D_; k0 += 64) {
        __syncthreads();
#pragma unroll
        for (int i = 0; i < 4; i++) {
            gload_lds16(Xf + aog[i] + k0, &sA[dbs[i]]);
            gload_lds16(Wf + bog[i] + k0, &sB[dbs[i]]);
        }
        __syncthreads();
#pragma unroll
        for (int kk = 0; kk < 2; kk++) {
            const f16x8 a0 = *(const f16x8*)&sA[aoff[kk][0]];
            const f16x8 a1 = *(const f16x8*)&sA[aoff[kk][1]];
#pragma unroll
            for (int n = 0; n < 8; n++) {
                const f16x8 bv = *(const f16x8*)&sB[boff[kk][n]];
                acc[0][n] = __builtin_amdgcn_mfma_f32_16x16x32_f16(a0, bv, acc[0][n], 0, 0, 0);
                acc[1][n] = __builtin_amdgcn_mfma_f32_16x16x32_f16(a1, bv, acc[1][n], 0, 0, 0);
            }
        }
    }

#pragma unroll
    for (int m = 0; m < 2; m++)
#pragma unroll
        for (int n = 0; n < 8; n++) {
            const int col = col0 + n * 16 + fr;
            const float bv = bias[col];
#pragma unroll
            for (int j = 0; j < 4; j++) {
                const int row = row0 + w * 32 + m * 16 + fg * 4 + j;
                const float y = fmaxf(acc[m][n][j] + bv, 0.f);
                Yf[(size_t)row * D_ + col] = f2h(y);
            }
        }
}

// ---------------------------------------------------------------------------
// K3: v fp32 [B][LV][D] -> vT fp16 [B][D][LV]  AND  vraw fp16 [B][LV][D]
__global__ __launch_bounds__(256) void transpose_v_kernel(
    const float* __restrict__ V, unsigned short* __restrict__ VT,
    unsigned short* __restrict__ Vraw) {
    __shared__ unsigned short s[64 * 72];
    const int b = blockIdx.z;
    const int v0 = blockIdx.x * 64, d0 = blockIdx.y * 64;
    const int t = threadIdx.x;
    {
        const int r = t >> 2, q = (t & 3) * 16;
        const float* src = V + ((size_t)b * LV_ + v0 + r) * D_ + d0 + q;
        unsigned short hb[16];
#pragma unroll
        for (int i = 0; i < 4; i++) {
            float4 x = ((const float4*)src)[i];
            hb[i * 4 + 0] = f2h(x.x);
            hb[i * 4 + 1] = f2h(x.y);
            hb[i * 4 + 2] = f2h(x.z);
            hb[i * 4 + 3] = f2h(x.w);
        }
#pragma unroll
        for (int j = 0; j < 16; j++) s[r * 72 + q + j] = hb[j];
        unsigned short* rdst = Vraw + ((size_t)b * LV_ + v0 + r) * D_ + d0 + q;
        ((ush8*)rdst)[0] = *(ush8*)&hb[0];
        ((ush8*)rdst)[1] = *(ush8*)&hb[8];
    }
    __syncthreads();
    {
        const int d = t >> 2, vq = (t & 3) * 16;
        ush8 t0, t1;
#pragma unroll
        for (int j = 0; j < 8; j++) t0[j] = (short)s[(vq + j) * 72 + d];
#pragma unroll
        for (int j = 0; j < 8; j++) t1[j] = (short)s[(vq + 8 + j) * 72 + d];
        unsigned short* dst = VT + ((size_t)b * D_ + d0 + d) * LV_ + v0 + vq;
        ((ush8*)dst)[0] = t0;
        ((ush8*)dst)[1] = t1;
    }
}

// ---------------------------------------------------------------------------
// K4: logits tile kernel. Grid (LU/128, NT, B). One 128x128 S-tile per WG,
// BK=64 (PV-proven staging/swizzle), per-tile softmax stats, P'=exp(S-m_t) fp16.
// Fully-masked tiles: stats only (PV skips those panels entirely).
__global__ __launch_bounds__(256, 2) void attn_logits_kernel(
    const unsigned short* __restrict__ Uf, const unsigned short* __restrict__ Vf,
    const int* __restrict__ lengths,
    unsigned short* __restrict__ Pp, float* __restrict__ m_used,
    float* __restrict__ Z_used) {
    __shared__ alignas(16) unsigned short sU[128 * 64], sV[128 * 64];
    const int b = blockIdx.z, ut = blockIdx.x, vt = blockIdx.y;
    const int t = threadIdx.x, lane = t & 63, w = t >> 6;
    const int fr = lane & 15, fg = lane >> 4;
    const int length = lengths[b];
    const int row0 = ut * 128, col0 = vt * 128;

    if (col0 >= length) {   // fully-masked tile: degenerate stats only
        if (t < 128) {
            const size_t row = (size_t)b * LU_ + row0 + t;
            m_used[row * NT_ + vt] = -__builtin_inff();
            Z_used[row * NT_ + vt] = 0.f;
        }
        return;
    }

    size_t aog[4], bog[4];
    int dbs[4];
#pragma unroll
    for (int i = 0; i < 4; i++) {
        const int r = w * 32 + i * 8 + (lane >> 3);
        const int cg = (lane & 7) ^ (r & 7);
        aog[i] = ((size_t)b * LU_ + row0 + r) * D_ + cg * 8;
        bog[i] = ((size_t)b * LV_ + col0 + r) * D_ + cg * 8;
        dbs[i] = (w * 32 + i * 8) * 64;
    }
    int aoff[2][2], boff[2][8];
#pragma unroll
    for (int kk = 0; kk < 2; kk++) {
#pragma unroll
        for (int m = 0; m < 2; m++) {
            const int r = w * 32 + m * 16 + fr;
            aoff[kk][m] = r * 64 + (((kk * 4 + fg) ^ (r & 7))) * 8;
        }
#pragma unroll
        for (int n = 0; n < 8; n++) {
            const int r = n * 16 + fr;
            boff[kk][n] = r * 64 + (((kk * 4 + fg) ^ (r & 7))) * 8;
        }
    }

    const f32x4 fzero = {0.f, 0.f, 0.f, 0.f};
    f32x4 acc[2][8];
#pragma unroll
    for (int m = 0; m < 2; m++)
#pragma unroll
        for (int n = 0; n < 8; n++) acc[m][n] = fzero;

#pragma unroll 1
    for (int k0 = 0; k0 < D_; k0 += 64) {
        __syncthreads();
#pragma unroll
        for (int i = 0; i < 4; i++) {
            gload_lds16(Uf + aog[i] + k0, &sU[dbs[i]]);
            gload_lds16(Vf + bog[i] + k0, &sV[dbs[i]]);
        }
        __syncthreads();
#pragma unroll
        for (int kk = 0; kk < 2; kk++) {
            const f16x8 a0 = *(const f16x8*)&sU[aoff[kk][0]];
            const f16x8 a1 = *(const f16x8*)&sU[aoff[kk][1]];
#pragma unroll
            for (int n = 0; n < 8; n++) {
                const f16x8 bv = *(const f16x8*)&sV[boff[kk][n]];
                acc[0][n] = __builtin_amdgcn_mfma_f32_16x16x32_f16(a0, bv, acc[0][n], 0, 0, 0);
                acc[1][n] = __builtin_amdgcn_mfma_f32_16x16x32_f16(a1, bv, acc[1][n], 0, 0, 0);
            }
        }
    }

    // per-tile stats: rows are wave-local (wave = 32 rows x 128 cols)
#pragma unroll
    for (int m = 0; m < 2; m++) {
        float mt[4] = {-__builtin_inff(), -__builtin_inff(), -__builtin_inff(), -__builtin_inff()};
#pragma unroll
        for (int n = 0; n < 8; n++) {
            const int col = col0 + n * 16 + fr;
            if (col < length) {
#pragma unroll
                for (int j = 0; j < 4; j++) mt[j] = fmaxf(mt[j], acc[m][n][j]);
            }
        }
#pragma unroll
        for (int d = 1; d < 16; d <<= 1) {
#pragma unroll
            for (int j = 0; j < 4; j++) mt[j] = fmaxf(mt[j], __shfl_xor(mt[j], d));
        }
        float rs[4] = {0.f, 0.f, 0.f, 0.f};
#pragma unroll
        for (int n = 0; n < 8; n++) {
            const int col = col0 + n * 16 + fr;
            const bool valid = (col < length);
#pragma unroll
            for (int j = 0; j < 4; j++) {
                const float p = valid ? __expf(acc[m][n][j] - mt[j]) : 0.f;
                rs[j] += p;
                const size_t row = (size_t)b * LU_ + row0 + w * 32 + m * 16 + fg * 4 + j;
                Pp[row * LV_ + col] = f2h(p);
            }
        }
#pragma unroll
        for (int d = 1; d < 16; d <<= 1) {
#pragma unroll
            for (int j = 0; j < 4; j++) rs[j] += __shfl_xor(rs[j], d);
        }
        if (fr == 0) {
#pragma unroll
            for (int j = 0; j < 4; j++) {
                const size_t row = (size_t)b * LU_ + row0 + w * 32 + m * 16 + fg * 4 + j;
                m_used[row * NT_ + vt] = mt[j];
                Z_used[row * NT_ + vt] = rs[j];
            }
        }
    }
}

// ---------------------------------------------------------------------------
// K5: combine per-tile stats -> Sc[row][vt] = exp(m_t - m_fin) / Z
__global__ __launch_bounds__(256) void stats_combine_kernel(
    const float* __restrict__ m_used, const float* __restrict__ Z_used,
    float* __restrict__ Sc) {
    const int row = blockIdx.x * 256 + threadIdx.x;
    float mv[NT_];
    float m = -__builtin_inff();
#pragma unroll
    for (int i = 0; i < NT_; i++) {
        mv[i] = m_used[(size_t)row * NT_ + i];
        m = fmaxf(m, mv[i]);
    }
    float ev[NT_];
    float z = 0.f;
#pragma unroll
    for (int i = 0; i < NT_; i++) {
        ev[i] = __expf(mv[i] - m);
        z += Z_used[(size_t)row * NT_ + i] * ev[i];
    }
    const float inv = 1.f / z;
#pragma unroll
    for (int i = 0; i < NT_; i++) Sc[(size_t)row * NT_ + i] = ev[i] * inv;
}

// ---------------------------------------------------------------------------
// K6: out = sum_vt (Sc(row,vt)*P'_vt) @ V_vt. 128x128 tile, BK=64,
// 4 waves 2x2 of 64x64, gload_lds + swizzle.
// Scale applied to the A-FRAGMENT (per-row, f16 pk-mul) -> direct MFMA
// accumulation, no part[]/fold. Sc panel preloaded to LDS (barrier before use!).
// Skips fully-masked v-tiles (contribution exactly zero).
__global__ __launch_bounds__(256, 4) void pv_gemm_kernel(
    const unsigned short* __restrict__ Pp, const unsigned short* __restrict__ VT,
    const float* __restrict__ Sc, const int* __restrict__ lengths,
    float* __restrict__ Out) {
    __shared__ alignas(16) unsigned short sA[128 * 64], sB[128 * 64];
    __shared__ float sSc[128 * NT_];
    const int b = blockIdx.z, bm = blockIdx.x, bn = blockIdx.y;
    const int t = threadIdx.x, lane = t & 63, w = t >> 6;
    const int wr = (w >> 1) * 64, wc = (w & 1) * 64;
    const int fr = lane & 15, fg = lane >> 4;
    const int length = lengths[b];
    const int ntv = (length + 127) >> 7;   // valid v-tiles (block-uniform)

    // preload this row-block's Sc panel: 128 rows x NT floats = 8 KB
    {
        const float* scg = Sc + ((size_t)b * LU_ + bm * 128) * NT_;
#pragma unroll
        for (int i = 0; i < (128 * NT_) / 256; i++)
            sSc[i * 256 + t] = scg[i * 256 + t];
    }
    __syncthreads();   // sSc is read cross-thread below (R7 bug: this was missing)

    // staging: wave w rows [w*32, +32), issue i in {0..3} rows [w*32+i*8, +8)
    size_t aog[4], bog[4];
    int dbs[4];
#pragma unroll
    for (int i = 0; i < 4; i++) {
        const int r = w * 32 + i * 8 + (lane >> 3);
        const int cg = (lane & 7) ^ (r & 7);
        aog[i] = ((size_t)b * LU_ + bm * 128 + r) * LV_ + cg * 8;
        bog[i] = ((size_t)b * D_ + bn * 128 + r) * LV_ + cg * 8;
        dbs[i] = (w * 32 + i * 8) * 64;
    }
    int aoff[2][4], boff[2][4];
#pragma unroll
    for (int kk = 0; kk < 2; kk++) {
#pragma unroll
        for (int m = 0; m < 4; m++) {
            const int r = wr + m * 16 + fr;
            aoff[kk][m] = r * 64 + (((kk * 4 + fg) ^ (r & 7))) * 8;
        }
#pragma unroll
        for (int n = 0; n < 4; n++) {
            const int r = wc + n * 16 + fr;
            boff[kk][n] = r * 64 + (((kk * 4 + fg) ^ (r & 7))) * 8;
        }
    }

    const f32x4 fzero = {0.f, 0.f, 0.f, 0.f};
    f32x4 acc[4][4];
#pragma unroll
    for (int m = 0; m < 4; m++)
#pragma unroll
        for (int n = 0; n < 4; n++) acc[m][n] = fzero;

#pragma unroll 1
    for (int vt = 0; vt < ntv; ++vt) {
        // per-row scale for this v-tile, as f16 splat (A-fragment row = wr+m*16+fr)
        f16x8 scv[4];
#pragma unroll
        for (int m = 0; m < 4; m++) {
            const _Float16 sh = (_Float16)sSc[(wr + m * 16 + fr) * NT_ + vt];
#pragma unroll
            for (int j = 0; j < 8; j++) scv[m][j] = sh;
        }

#pragma unroll 1
        for (int kb = 0; kb < 2; ++kb) {
            const int k0 = vt * 128 + kb * 64;
            __syncthreads();
#pragma unroll
            for (int i = 0; i < 4; i++) {
                gload_lds16(Pp + aog[i] + k0, &sA[dbs[i]]);
                gload_lds16(VT + bog[i] + k0, &sB[dbs[i]]);
            }
            __syncthreads();
#pragma unroll
            for (int kk = 0; kk < 2; kk++) {
                f16x8 af[4];
#pragma unroll
                for (int m = 0; m < 4; m++)
                    af[m] = (*(const f16x8*)&sA[aoff[kk][m]]) * scv[m];
#pragma unroll
                for (int n = 0; n < 4; n++) {
                    const f16x8 bv = *(const f16x8*)&sB[boff[kk][n]];
#pragma unroll
                    for (int m = 0; m < 4; m++)
                        acc[m][n] = __builtin_amdgcn_mfma_f32_16x16x32_f16(af[m], bv, acc[m][n], 0, 0, 0);
                }
            }
        }
    }

    float* Ob = Out + (size_t)b * LU_ * D_;
#pragma unroll
    for (int m = 0; m < 4; m++) {
        const int rbase = bm * 128 + wr + m * 16 + fg * 4;
#pragma unroll
        for (int n = 0; n < 4; n++) {
            const int col = bn * 128 + wc + n * 16 + fr;
#pragma unroll
            for (int j = 0; j < 4; j++)
                Ob[(size_t)(rbase + j) * D_ + col] = acc[m][n][j];
        }
    }
}

// ---------------------------------------------------------------------------
extern "C" void kernel_launch(void* const* d_in, const int* in_sizes, int n_in,
                              void* d_out, int out_size, void* d_ws, size_t ws_size,
                              hipStream_t stream) {
    (void)in_sizes; (void)n_in; (void)out_size; (void)ws_size;
    const float* u    = (const float*)d_in[0];
    const float* v    = (const float*)d_in[1];
    const void*  vm   = d_in[2];
    const float* W    = (const float*)d_in[3];
    const float* bias = (const float*)d_in[4];
    float* out = (float*)d_out;
    char* ws = (char*)d_ws;

    // ws layout (~457 MB)
    unsigned short* Pp    = (unsigned short*)(ws + 0 * MB_);     // 128MB fp16
    unsigned short* vT    = (unsigned short*)(ws + 128 * MB_);   // 64MB fp16
    unsigned short* u_f   = (unsigned short*)(ws + 192 * MB_);   // 64MB u_ fp16
    unsigned short* v_f   = (unsigned short*)(ws + 256 * MB_);   // 64MB v_ fp16
    unsigned short* vraw  = (unsigned short*)(ws + 320 * MB_);   // 64MB raw v fp16
    unsigned short* xs_u  = (unsigned short*)(ws + 384 * MB_);   // 64MB raw u fp16
    unsigned short* W_f   = (unsigned short*)(ws + 448 * MB_);   // 2MB
    int*   lengths = (int*)(ws + 450 * MB_);
    float* m_used  = (float*)(ws + 451 * MB_);                   // 2MB
    float* Z_used  = (float*)(ws + 453 * MB_);                   // 2MB
    float* Sc      = (float*)(ws + 455 * MB_);                   // 2MB

    const long nW8 = (long)D_ * D_ / 8;
    const long nX8 = (long)B_ * LU_ * D_ / 8;

    lengths_kernel<<<1, 256, 0, stream>>>(vm, lengths);
    cvt_kernel<<<512, 256, 0, stream>>>(W, W_f, nW8);
    cvt_kernel<<<4096, 256, 0, stream>>>(u, xs_u, nX8);
    proj_kernel<<<dim3(B_ * LU_ / 128, D_ / 128), 256, 0, stream>>>(
        xs_u, W_f, bias, lengths, 0, u_f);
    transpose_v_kernel<<<dim3(LV_ / 64, D_ / 64, B_), 256, 0, stream>>>(v, vT, vraw);
    proj_kernel<<<dim3(B_ * LV_ / 128, D_ / 128), 256, 0, stream>>>(
        vraw, W_f, bias, lengths, 1, v_f);
    attn_logits_kernel<<<dim3(LU_ / 128, NT_, B_), 256, 0, stream>>>(
        u_f, v_f, lengths, Pp, m_used, Z_used);
    stats_combine_kernel<<<B_ * LU_ / 256, 256, 0, stream>>>(m_used, Z_used, Sc);
    pv_gemm_kernel<<<dim3(LU_ / 128, D_ / 128, B_), 256, 0, stream>>>(Pp, vT, Sc, lengths, out);
}